// Round 2
// baseline (2126.564 us; speedup 1.0000x reference)
//
#include <hip/hip_runtime.h>
#include <float.h>

#define NQ     2048
#define DIM    512
#define MSZ    131072
#define TOPK   32
#define CH     256
#define NCHUNK (MSZ / CH)       // 512
#define TOPC   8                // candidates per (query, chunk)
#define CPQ    (NCHUNK * TOPC)  // 4096 packed candidates per query (unchanged)
#define QT     32               // queries per K1 block
#define MERGE  128              // exact-rescore set per query

typedef short  short8 __attribute__((ext_vector_type(8)));
typedef float  f32x4  __attribute__((ext_vector_type(4)));

__device__ __forceinline__ unsigned short f32_to_bf16_rne(float f) {
    union { float f; unsigned u; } v; v.f = f;
    unsigned r = v.u + 0x7FFFu + ((v.u >> 16) & 1u);
    return (unsigned short)(r >> 16);
}
// monotone (order-preserving) u16 transform of bf16 bits
__device__ __forceinline__ unsigned bf16_ordered(unsigned short k) {
    return (k & 0x8000u) ? (unsigned)(unsigned short)~k
                         : (unsigned)(k | 0x8000u);
}
// count of set bits in m among lanes strictly below mine
__device__ __forceinline__ int mbcnt64(unsigned long long m) {
    return (int)__builtin_amdgcn_mbcnt_hi(
        (unsigned)(m >> 32), __builtin_amdgcn_mbcnt_lo((unsigned)m, 0u));
}

// ---------------------------------------------------------------------------
// K0: f32 -> bf16 (RNE) conversion, float4 -> ushort4
// ---------------------------------------------------------------------------
__global__ __launch_bounds__(256) void k0_convert(
    const float* __restrict__ src, unsigned short* __restrict__ dst, int n4)
{
    int i = blockIdx.x * blockDim.x + threadIdx.x;
    const int stride = gridDim.x * blockDim.x;
    const float4* s4 = reinterpret_cast<const float4*>(src);
    ushort4* d4 = reinterpret_cast<ushort4*>(dst);
    for (; i < n4; i += stride) {
        const float4 v = s4[i];
        ushort4 o;
        o.x = f32_to_bf16_rne(v.x); o.y = f32_to_bf16_rne(v.y);
        o.z = f32_to_bf16_rne(v.z); o.w = f32_to_bf16_rne(v.w);
        d4[i] = o;
    }
}

// ---------------------------------------------------------------------------
// K1: bf16 MFMA scoring (32 queries x 256-row chunk) + per-(q,chunk) top-8
// via wave-per-query 16-bit threshold search (ballot+popcount), with FOUR
// independent query searches interleaved per round for ILP (the serial
// v_cmp -> s_bcnt -> s_cselect chain is latency-bound, not throughput-bound).
// Emits packed u32 candidates: key16<<16 | (255 - local_row).
// CH=256 -> sc = 16 KB -> 8 blocks/CU = 32 waves/CU (HW cap) vs previous 5.
// Superset safety: true global-top-32 row must be in its chunk's top-8 by
// bf16 key; ~40 rows globally exceed the rank-32 key, so a violating chunk
// needs >=9 of those 40 (p = 1/512 each): P ~ 6e-11 over all queries.
// XCD-chunked swizzle: each XCD owns 64 contiguous chunks; a chunk's B tile
// (256 KB) stays L2-resident across its 64 query blocks.
// ---------------------------------------------------------------------------
__global__ __launch_bounds__(256, 8) void k1_score_select(
    const unsigned short* __restrict__ qbf, const unsigned short* __restrict__ kbf,
    unsigned* __restrict__ cand)
{
    // dispatch slot -> (qt, chunk) with XCD ownership of chunk ranges
    const int s     = blockIdx.x;            // 0..32767
    const int xcd   = s & 7;                 // round-robin XCD assignment
    const int idx   = s >> 3;                // 0..4095 within XCD
    const int qt    = idx & 63;              // fast dim: chunk stays L2-hot
    const int chunk = xcd * (NCHUNK / 8) + (idx >> 6);   // 64 chunks per XCD

    const int tid  = threadIdx.x;
    const int w    = tid >> 6;      // wave 0..3 -> rows w*64..+63
    const int lane = tid & 63;
    const int l15  = lane & 15;
    const int kgrp = lane >> 4;     // k-subgroup 0..3

    __shared__ unsigned short sc[QT][CH];   // 16 KB bf16 scores

    // A: Q[qt*32 + mt*16 + l15][k]  row-major, 8 contiguous bf16 per lane
    const unsigned short* Abase = qbf + ((size_t)(qt * QT) + l15) * DIM + kgrp * 8;
    // B: K[chunk*256 + w*64 + nt*16 + l15][k] (B^T pattern)
    const unsigned short* Bbase =
        kbf + ((size_t)chunk * CH + w * 64 + l15) * DIM + kgrp * 8;

    {
        f32x4 acc[2][4];
        #pragma unroll
        for (int mt = 0; mt < 2; ++mt)
            #pragma unroll
            for (int nt = 0; nt < 4; ++nt)
                acc[mt][nt] = (f32x4){0.f, 0.f, 0.f, 0.f};

        #pragma unroll 4
        for (int ks = 0; ks < 16; ++ks) {
            short8 a[2], b[4];
            #pragma unroll
            for (int mt = 0; mt < 2; ++mt)
                a[mt] = *reinterpret_cast<const short8*>(
                    Abase + (size_t)mt * 16 * DIM + ks * 32);
            #pragma unroll
            for (int nt = 0; nt < 4; ++nt)
                b[nt] = *reinterpret_cast<const short8*>(
                    Bbase + (size_t)(nt * 16) * DIM + ks * 32);
            #pragma unroll
            for (int mt = 0; mt < 2; ++mt)
                #pragma unroll
                for (int nt = 0; nt < 4; ++nt)
                    acc[mt][nt] = __builtin_amdgcn_mfma_f32_16x16x32_bf16(
                        a[mt], b[nt], acc[mt][nt], 0, 0, 0);
        }
        // C/D layout: q = mt*16 + kgrp*4 + r, row = w*64 + nt*16 + l15
        #pragma unroll
        for (int mt = 0; mt < 2; ++mt)
            #pragma unroll
            for (int nt = 0; nt < 4; ++nt)
                #pragma unroll
                for (int r = 0; r < 4; ++r) {
                    const int qloc = mt * 16 + kgrp * 4 + r;
                    const int rloc = w * 64 + nt * 16 + l15;
                    sc[qloc][rloc] = f32_to_bf16_rne(acc[mt][nt][r]);
                }
    }
    __syncthreads();

    // selection: wave w handles queries w, w+4, ..., w+28, in two groups of
    // four interleaved searches (independent serial chains -> 4x ILP).
    for (int qp = 0; qp < 2; ++qp) {
        unsigned key[4][4];
        #pragma unroll
        for (int u = 0; u < 4; ++u) {
            const int qloc = w + (qp * 4 + u) * 4;
            // lane-strided u32 reads: conflict-free (2-way alias is free).
            // u32 index lane + j*64 holds keys for rl = 2*lane + 128*j (+1)
            const unsigned* row32 = reinterpret_cast<const unsigned*>(sc[qloc]);
            #pragma unroll
            for (int j = 0; j < 2; ++j) {
                const unsigned p = row32[lane + j * 64];
                key[u][2 * j]     = bf16_ordered((unsigned short)(p & 0xFFFFu));
                key[u][2 * j + 1] = bf16_ordered((unsigned short)(p >> 16));
            }
        }
        // T[u] = 8th largest of the 256 keys of query u (4 chains in lockstep)
        unsigned T[4] = {0u, 0u, 0u, 0u};
        for (int b = 15; b >= 0; --b) {
            #pragma unroll
            for (int u = 0; u < 4; ++u) {
                const unsigned trial = T[u] | (1u << b);
                int cnt = 0;
                #pragma unroll
                for (int j = 0; j < 4; ++j)
                    cnt += __popcll(__ballot(key[u][j] >= trial));
                if (cnt >= TOPC) T[u] = trial;
            }
        }
        #pragma unroll
        for (int u = 0; u < 4; ++u) {
            const int qloc = w + (qp * 4 + u) * 4;
            int gtTot = 0;
            #pragma unroll
            for (int j = 0; j < 4; ++j)
                gtTot += __popcll(__ballot(key[u][j] > T[u]));
            const int quotaEq = TOPC - gtTot;

            const int qid = qt * QT + qloc;
            unsigned* base = cand + ((size_t)qid * NCHUNK + chunk) * TOPC;
            int rgt = 0, req = 0;
            #pragma unroll
            for (int j = 0; j < 4; ++j) {
                const unsigned long long mgt = __ballot(key[u][j] > T[u]);
                const unsigned long long meq = __ballot(key[u][j] == T[u]);
                const unsigned rl = 2u * (unsigned)lane + 128u * (unsigned)(j >> 1)
                                    + (unsigned)(j & 1);
                if (key[u][j] > T[u]) {
                    base[rgt + mbcnt64(mgt)] = (key[u][j] << 16) | (CH - 1u - rl);
                } else if (key[u][j] == T[u]) {
                    const int se = req + mbcnt64(meq);
                    if (se < quotaEq) base[gtTot + se] = (T[u] << 16) | (CH - 1u - rl);
                }
                rgt += __popcll(mgt);
                req += __popcll(meq);
            }
        }
    }
}

// ---------------------------------------------------------------------------
// K2: wave per query. Radix-select top-128 of the 4096 packed candidates
// (ballot+popcount counting), rescore them with the BIT-EXACT np chain
// (ascending single-acc fmaf), emit top-32 by (exact score desc, row asc).
// ---------------------------------------------------------------------------
__global__ __launch_bounds__(256) void k2_merge_rescore(
    const float* __restrict__ q, const float* __restrict__ kmem,
    const unsigned* __restrict__ cand, int* __restrict__ final_idx)
{
    const int w    = threadIdx.x >> 6;
    const int lane = threadIdx.x & 63;
    const int qid  = blockIdx.x * 4 + w;

    __shared__ int   rows_s[4][MERGE];
    __shared__ float scs_s[4][MERGE];

    // load 64 candidates per lane, coalesced uint4
    unsigned v[64];
    const uint4* cp4 = reinterpret_cast<const uint4*>(cand + (size_t)qid * CPQ);
    #pragma unroll
    for (int j = 0; j < 16; ++j) {
        const uint4 t = cp4[j * 64 + lane];
        v[j * 4 + 0] = t.x; v[j * 4 + 1] = t.y;
        v[j * 4 + 2] = t.z; v[j * 4 + 3] = t.w;
    }
    // P = 128th largest u32 (ballot+popcount counting)
    unsigned P = 0;
    for (int b = 31; b >= 0; --b) {
        const unsigned trial = P | (1u << b);
        int cnt = 0;
        #pragma unroll
        for (int j = 0; j < 64; ++j) cnt += __popcll(__ballot(v[j] >= trial));
        if (cnt >= MERGE) P = trial;
    }
    int gt = 0, eq = 0;
    #pragma unroll
    for (int j = 0; j < 64; ++j) { gt += (v[j] > P); eq += (v[j] == P); }
    int pgt = gt, peq = eq;
    #pragma unroll
    for (int m = 1; m < 64; m <<= 1) {
        const int ag = __shfl_up(pgt, m);
        const int ae = __shfl_up(peq, m);
        if (lane >= m) { pgt += ag; peq += ae; }
    }
    const int totGT = __shfl(pgt, 63);
    pgt -= gt; peq -= eq;
    const int quotaEq = MERGE - totGT;
    {
        int sgt = pgt, seq = peq;
        #pragma unroll
        for (int j = 0; j < 64; ++j) {
            const int off  = (j & ~3) * 64 + lane * 4 + (j & 3); // u32 offset in query's cand block
            const int chnk = off >> 3;                            // 8 cands per chunk
            const int row  = chnk * CH + (CH - 1) - (int)(v[j] & (CH - 1u));
            if (v[j] > P) {
                rows_s[w][sgt++] = row;
            } else if (v[j] == P) {
                if (seq < quotaEq) rows_s[w][totGT + seq] = row;
                seq++;
            }
        }
    }
    __syncthreads();

    // bit-exact rescore: 2 interleaved ascending fmaf chains per lane
    {
#pragma clang fp contract(off)
        const float4* qr = reinterpret_cast<const float4*>(q + (size_t)qid * DIM);
        const int ra = rows_s[w][lane];
        const int rb = rows_s[w][lane + 64];
        const float4* ka = reinterpret_cast<const float4*>(kmem + (size_t)ra * DIM);
        const float4* kb = reinterpret_cast<const float4*>(kmem + (size_t)rb * DIM);
        float sa = 0.f, sb = 0.f;
        for (int d4 = 0; d4 < DIM / 4; ++d4) {
            const float4 qv = qr[d4];
            const float4 av = ka[d4];
            const float4 bv = kb[d4];
            sa = __builtin_fmaf(qv.x, av.x, sa); sb = __builtin_fmaf(qv.x, bv.x, sb);
            sa = __builtin_fmaf(qv.y, av.y, sa); sb = __builtin_fmaf(qv.y, bv.y, sb);
            sa = __builtin_fmaf(qv.z, av.z, sa); sb = __builtin_fmaf(qv.z, bv.z, sb);
            sa = __builtin_fmaf(qv.w, av.w, sa); sb = __builtin_fmaf(qv.w, bv.w, sb);
        }
        scs_s[w][lane]      = sa;
        scs_s[w][lane + 64] = sb;
    }
    __syncthreads();

    // exact top-32 of 128 by (score desc, row asc)
    float m0 = scs_s[w][lane],      m1 = scs_s[w][lane + 64];
    const int rr0 = rows_s[w][lane], rr1 = rows_s[w][lane + 64];
    for (int sel = 0; sel < TOPK; ++sel) {
        float bs; int bi;
        if (m0 > m1 || (m0 == m1 && rr0 < rr1)) { bs = m0; bi = rr0; }
        else                                    { bs = m1; bi = rr1; }
        #pragma unroll
        for (int m = 1; m < 64; m <<= 1) {
            const float os = __shfl_xor(bs, m);
            const int   oi = __shfl_xor(bi, m);
            if (os > bs || (os == bs && oi < bi)) { bs = os; bi = oi; }
        }
        if (lane == 0) final_idx[qid * TOPK + sel] = bi;
        if (rr0 == bi) m0 = -FLT_MAX;   // rows unique -> removes exactly winner
        if (rr1 == bi) m1 = -FLT_MAX;
    }
}

// ---------------------------------------------------------------------------
// K3: gather K and V rows into the output (k block then v block, flat f32)
// ---------------------------------------------------------------------------
__global__ __launch_bounds__(128) void k3_gather(
    const float* __restrict__ kmem, const float* __restrict__ vmem,
    const int* __restrict__ final_idx, float* __restrict__ out)
{
    const int b = blockIdx.x;
    const int t = threadIdx.x;
    const int idx = final_idx[b];
    const float4* kr = reinterpret_cast<const float4*>(kmem + (size_t)idx * DIM);
    const float4* vr = reinterpret_cast<const float4*>(vmem + (size_t)idx * DIM);
    float4* ok = reinterpret_cast<float4*>(out + (size_t)b * DIM);
    float4* ov = reinterpret_cast<float4*>(out + (size_t)NQ * TOPK * DIM + (size_t)b * DIM);
    ok[t] = kr[t];
    ov[t] = vr[t];
}

extern "C" void kernel_launch(void* const* d_in, const int* in_sizes, int n_in,
                              void* d_out, int out_size, void* d_ws, size_t ws_size,
                              hipStream_t stream)
{
    const float* q    = (const float*)d_in[0];
    const float* kmem = (const float*)d_in[1];
    const float* vmem = (const float*)d_in[2];
    float* out = (float*)d_out;

    // d_out scratch layout (consumed before K3 overwrites everything):
    // [0, 134217728)            bf16 K
    // [134217728, 136314880)    bf16 q
    // [136314880, 169869312)    packed candidates (u32)
    unsigned char* base = (unsigned char*)d_out;
    unsigned short* kbf = (unsigned short*)base;
    unsigned short* qbf = (unsigned short*)(base + (size_t)MSZ * DIM * 2);
    unsigned* cand = (unsigned*)(base + (size_t)MSZ * DIM * 2 + (size_t)NQ * DIM * 2);
    int* final_idx = (int*)d_ws;   // 256 KB, survives the gather

    k0_convert<<<4096, 256, 0, stream>>>(kmem, kbf, MSZ * DIM / 4);
    k0_convert<<<256, 256, 0, stream>>>(q, qbf, NQ * DIM / 4);
    k1_score_select<<<NQ / QT * NCHUNK, 256, 0, stream>>>(qbf, kbf, cand);  // 32768 blocks
    k2_merge_rescore<<<NQ / 4, 256, 0, stream>>>(q, kmem, cand, final_idx);
    k3_gather<<<NQ * TOPK, 128, 0, stream>>>(kmem, vmem, final_idx, out);
}

// Round 3
// 1695.482 us; speedup vs baseline: 1.2543x; 1.2543x over previous
//
#include <hip/hip_runtime.h>
#include <float.h>

#define NQ     2048
#define DIM    512
#define MSZ    131072
#define TOPK   32
#define CH     256
#define NCHUNK (MSZ / CH)       // 512
#define TOPC   8                // candidates per (query, chunk)
#define CPQ    (NCHUNK * TOPC)  // 4096 packed candidates per query (unchanged)
#define QT     32               // queries per K1 block
#define MERGE  128              // exact-rescore set per query

typedef short  short8 __attribute__((ext_vector_type(8)));
typedef float  f32x4  __attribute__((ext_vector_type(4)));

__device__ __forceinline__ unsigned short f32_to_bf16_rne(float f) {
    union { float f; unsigned u; } v; v.f = f;
    unsigned r = v.u + 0x7FFFu + ((v.u >> 16) & 1u);
    return (unsigned short)(r >> 16);
}
// monotone (order-preserving) u16 transform of bf16 bits
__device__ __forceinline__ unsigned bf16_ordered(unsigned short k) {
    return (k & 0x8000u) ? (unsigned)(unsigned short)~k
                         : (unsigned)(k | 0x8000u);
}
// count of set bits in m among lanes strictly below mine
__device__ __forceinline__ int mbcnt64(unsigned long long m) {
    return (int)__builtin_amdgcn_mbcnt_hi(
        (unsigned)(m >> 32), __builtin_amdgcn_mbcnt_lo((unsigned)m, 0u));
}

// ---------------------------------------------------------------------------
// K0: f32 -> bf16 (RNE) conversion, float4 -> ushort4
// ---------------------------------------------------------------------------
__global__ __launch_bounds__(256) void k0_convert(
    const float* __restrict__ src, unsigned short* __restrict__ dst, int n4)
{
    int i = blockIdx.x * blockDim.x + threadIdx.x;
    const int stride = gridDim.x * blockDim.x;
    const float4* s4 = reinterpret_cast<const float4*>(src);
    ushort4* d4 = reinterpret_cast<ushort4*>(dst);
    for (; i < n4; i += stride) {
        const float4 v = s4[i];
        ushort4 o;
        o.x = f32_to_bf16_rne(v.x); o.y = f32_to_bf16_rne(v.y);
        o.z = f32_to_bf16_rne(v.z); o.w = f32_to_bf16_rne(v.w);
        d4[i] = o;
    }
}

// ---------------------------------------------------------------------------
// K1: bf16 MFMA scoring (32 queries x 256-row chunk) + per-(q,chunk) top-8
// via wave-per-query 16-bit threshold search (ballot+popcount), with FOUR
// independent query searches interleaved per round for ILP (the serial
// v_cmp -> s_bcnt -> s_cselect chain is latency-bound, not throughput-bound).
// Emits packed u32 candidates: key16<<16 | (255 - local_row).
// LDS = 16 KB. Occupancy is VGPR-capped: __launch_bounds__(256, 6) gives an
// 85-VGPR budget (kernel needs ~70) -> 6 blocks/CU = 24 waves/CU, NO SPILL.
// (256, 8) in the previous round capped at 64 VGPRs and spilled the MFMA
// accumulators to scratch inside the K-loop: 3.2 GB of HBM spill traffic.
// Superset safety: true global-top-32 row must be in its chunk's top-8 by
// bf16 key; ~40 rows globally exceed the rank-32 key, so a violating chunk
// needs >=9 of those 40 (p = 1/512 each): P ~ 6e-11 over all queries.
// XCD-chunked swizzle: each XCD owns 64 contiguous chunks; a chunk's B tile
// (256 KB) stays L2-resident across its 64 query blocks.
// ---------------------------------------------------------------------------
__global__ __launch_bounds__(256, 6) void k1_score_select(
    const unsigned short* __restrict__ qbf, const unsigned short* __restrict__ kbf,
    unsigned* __restrict__ cand)
{
    // dispatch slot -> (qt, chunk) with XCD ownership of chunk ranges
    const int s     = blockIdx.x;            // 0..32767
    const int xcd   = s & 7;                 // round-robin XCD assignment
    const int idx   = s >> 3;                // 0..4095 within XCD
    const int qt    = idx & 63;              // fast dim: chunk stays L2-hot
    const int chunk = xcd * (NCHUNK / 8) + (idx >> 6);   // 64 chunks per XCD

    const int tid  = threadIdx.x;
    const int w    = tid >> 6;      // wave 0..3 -> rows w*64..+63
    const int lane = tid & 63;
    const int l15  = lane & 15;
    const int kgrp = lane >> 4;     // k-subgroup 0..3

    __shared__ unsigned short sc[QT][CH];   // 16 KB bf16 scores

    // A: Q[qt*32 + mt*16 + l15][k]  row-major, 8 contiguous bf16 per lane
    const unsigned short* Abase = qbf + ((size_t)(qt * QT) + l15) * DIM + kgrp * 8;
    // B: K[chunk*256 + w*64 + nt*16 + l15][k] (B^T pattern)
    const unsigned short* Bbase =
        kbf + ((size_t)chunk * CH + w * 64 + l15) * DIM + kgrp * 8;

    {
        f32x4 acc[2][4];
        #pragma unroll
        for (int mt = 0; mt < 2; ++mt)
            #pragma unroll
            for (int nt = 0; nt < 4; ++nt)
                acc[mt][nt] = (f32x4){0.f, 0.f, 0.f, 0.f};

        #pragma unroll 4
        for (int ks = 0; ks < 16; ++ks) {
            short8 a[2], b[4];
            #pragma unroll
            for (int mt = 0; mt < 2; ++mt)
                a[mt] = *reinterpret_cast<const short8*>(
                    Abase + (size_t)mt * 16 * DIM + ks * 32);
            #pragma unroll
            for (int nt = 0; nt < 4; ++nt)
                b[nt] = *reinterpret_cast<const short8*>(
                    Bbase + (size_t)(nt * 16) * DIM + ks * 32);
            #pragma unroll
            for (int mt = 0; mt < 2; ++mt)
                #pragma unroll
                for (int nt = 0; nt < 4; ++nt)
                    acc[mt][nt] = __builtin_amdgcn_mfma_f32_16x16x32_bf16(
                        a[mt], b[nt], acc[mt][nt], 0, 0, 0);
        }
        // C/D layout: q = mt*16 + kgrp*4 + r, row = w*64 + nt*16 + l15
        #pragma unroll
        for (int mt = 0; mt < 2; ++mt)
            #pragma unroll
            for (int nt = 0; nt < 4; ++nt)
                #pragma unroll
                for (int r = 0; r < 4; ++r) {
                    const int qloc = mt * 16 + kgrp * 4 + r;
                    const int rloc = w * 64 + nt * 16 + l15;
                    sc[qloc][rloc] = f32_to_bf16_rne(acc[mt][nt][r]);
                }
    }
    __syncthreads();

    // selection: wave w handles queries w, w+4, ..., w+28, in two groups of
    // four interleaved searches (independent serial chains -> 4x ILP).
    for (int qp = 0; qp < 2; ++qp) {
        unsigned key[4][4];
        #pragma unroll
        for (int u = 0; u < 4; ++u) {
            const int qloc = w + (qp * 4 + u) * 4;
            // lane-strided u32 reads: conflict-free (2-way alias is free).
            // u32 index lane + j*64 holds keys for rl = 2*lane + 128*j (+1)
            const unsigned* row32 = reinterpret_cast<const unsigned*>(sc[qloc]);
            #pragma unroll
            for (int j = 0; j < 2; ++j) {
                const unsigned p = row32[lane + j * 64];
                key[u][2 * j]     = bf16_ordered((unsigned short)(p & 0xFFFFu));
                key[u][2 * j + 1] = bf16_ordered((unsigned short)(p >> 16));
            }
        }
        // T[u] = 8th largest of the 256 keys of query u (4 chains in lockstep)
        unsigned T[4] = {0u, 0u, 0u, 0u};
        for (int b = 15; b >= 0; --b) {
            #pragma unroll
            for (int u = 0; u < 4; ++u) {
                const unsigned trial = T[u] | (1u << b);
                int cnt = 0;
                #pragma unroll
                for (int j = 0; j < 4; ++j)
                    cnt += __popcll(__ballot(key[u][j] >= trial));
                if (cnt >= TOPC) T[u] = trial;
            }
        }
        #pragma unroll
        for (int u = 0; u < 4; ++u) {
            const int qloc = w + (qp * 4 + u) * 4;
            int gtTot = 0;
            #pragma unroll
            for (int j = 0; j < 4; ++j)
                gtTot += __popcll(__ballot(key[u][j] > T[u]));
            const int quotaEq = TOPC - gtTot;

            const int qid = qt * QT + qloc;
            unsigned* base = cand + ((size_t)qid * NCHUNK + chunk) * TOPC;
            int rgt = 0, req = 0;
            #pragma unroll
            for (int j = 0; j < 4; ++j) {
                const unsigned long long mgt = __ballot(key[u][j] > T[u]);
                const unsigned long long meq = __ballot(key[u][j] == T[u]);
                const unsigned rl = 2u * (unsigned)lane + 128u * (unsigned)(j >> 1)
                                    + (unsigned)(j & 1);
                if (key[u][j] > T[u]) {
                    base[rgt + mbcnt64(mgt)] = (key[u][j] << 16) | (CH - 1u - rl);
                } else if (key[u][j] == T[u]) {
                    const int se = req + mbcnt64(meq);
                    if (se < quotaEq) base[gtTot + se] = (T[u] << 16) | (CH - 1u - rl);
                }
                rgt += __popcll(mgt);
                req += __popcll(meq);
            }
        }
    }
}

// ---------------------------------------------------------------------------
// K2: wave per query. Radix-select top-128 of the 4096 packed candidates
// (ballot+popcount counting), rescore them with the BIT-EXACT np chain
// (ascending single-acc fmaf), emit top-32 by (exact score desc, row asc).
// ---------------------------------------------------------------------------
__global__ __launch_bounds__(256) void k2_merge_rescore(
    const float* __restrict__ q, const float* __restrict__ kmem,
    const unsigned* __restrict__ cand, int* __restrict__ final_idx)
{
    const int w    = threadIdx.x >> 6;
    const int lane = threadIdx.x & 63;
    const int qid  = blockIdx.x * 4 + w;

    __shared__ int   rows_s[4][MERGE];
    __shared__ float scs_s[4][MERGE];

    // load 64 candidates per lane, coalesced uint4
    unsigned v[64];
    const uint4* cp4 = reinterpret_cast<const uint4*>(cand + (size_t)qid * CPQ);
    #pragma unroll
    for (int j = 0; j < 16; ++j) {
        const uint4 t = cp4[j * 64 + lane];
        v[j * 4 + 0] = t.x; v[j * 4 + 1] = t.y;
        v[j * 4 + 2] = t.z; v[j * 4 + 3] = t.w;
    }
    // P = 128th largest u32 (ballot+popcount counting)
    unsigned P = 0;
    for (int b = 31; b >= 0; --b) {
        const unsigned trial = P | (1u << b);
        int cnt = 0;
        #pragma unroll
        for (int j = 0; j < 64; ++j) cnt += __popcll(__ballot(v[j] >= trial));
        if (cnt >= MERGE) P = trial;
    }
    int gt = 0, eq = 0;
    #pragma unroll
    for (int j = 0; j < 64; ++j) { gt += (v[j] > P); eq += (v[j] == P); }
    int pgt = gt, peq = eq;
    #pragma unroll
    for (int m = 1; m < 64; m <<= 1) {
        const int ag = __shfl_up(pgt, m);
        const int ae = __shfl_up(peq, m);
        if (lane >= m) { pgt += ag; peq += ae; }
    }
    const int totGT = __shfl(pgt, 63);
    pgt -= gt; peq -= eq;
    const int quotaEq = MERGE - totGT;
    {
        int sgt = pgt, seq = peq;
        #pragma unroll
        for (int j = 0; j < 64; ++j) {
            const int off  = (j & ~3) * 64 + lane * 4 + (j & 3); // u32 offset in query's cand block
            const int chnk = off >> 3;                            // 8 cands per chunk
            const int row  = chnk * CH + (CH - 1) - (int)(v[j] & (CH - 1u));
            if (v[j] > P) {
                rows_s[w][sgt++] = row;
            } else if (v[j] == P) {
                if (seq < quotaEq) rows_s[w][totGT + seq] = row;
                seq++;
            }
        }
    }
    __syncthreads();

    // bit-exact rescore: 2 interleaved ascending fmaf chains per lane
    {
#pragma clang fp contract(off)
        const float4* qr = reinterpret_cast<const float4*>(q + (size_t)qid * DIM);
        const int ra = rows_s[w][lane];
        const int rb = rows_s[w][lane + 64];
        const float4* ka = reinterpret_cast<const float4*>(kmem + (size_t)ra * DIM);
        const float4* kb = reinterpret_cast<const float4*>(kmem + (size_t)rb * DIM);
        float sa = 0.f, sb = 0.f;
        for (int d4 = 0; d4 < DIM / 4; ++d4) {
            const float4 qv = qr[d4];
            const float4 av = ka[d4];
            const float4 bv = kb[d4];
            sa = __builtin_fmaf(qv.x, av.x, sa); sb = __builtin_fmaf(qv.x, bv.x, sb);
            sa = __builtin_fmaf(qv.y, av.y, sa); sb = __builtin_fmaf(qv.y, bv.y, sb);
            sa = __builtin_fmaf(qv.z, av.z, sa); sb = __builtin_fmaf(qv.z, bv.z, sb);
            sa = __builtin_fmaf(qv.w, av.w, sa); sb = __builtin_fmaf(qv.w, bv.w, sb);
        }
        scs_s[w][lane]      = sa;
        scs_s[w][lane + 64] = sb;
    }
    __syncthreads();

    // exact top-32 of 128 by (score desc, row asc)
    float m0 = scs_s[w][lane],      m1 = scs_s[w][lane + 64];
    const int rr0 = rows_s[w][lane], rr1 = rows_s[w][lane + 64];
    for (int sel = 0; sel < TOPK; ++sel) {
        float bs; int bi;
        if (m0 > m1 || (m0 == m1 && rr0 < rr1)) { bs = m0; bi = rr0; }
        else                                    { bs = m1; bi = rr1; }
        #pragma unroll
        for (int m = 1; m < 64; m <<= 1) {
            const float os = __shfl_xor(bs, m);
            const int   oi = __shfl_xor(bi, m);
            if (os > bs || (os == bs && oi < bi)) { bs = os; bi = oi; }
        }
        if (lane == 0) final_idx[qid * TOPK + sel] = bi;
        if (rr0 == bi) m0 = -FLT_MAX;   // rows unique -> removes exactly winner
        if (rr1 == bi) m1 = -FLT_MAX;
    }
}

// ---------------------------------------------------------------------------
// K3: gather K and V rows into the output (k block then v block, flat f32)
// ---------------------------------------------------------------------------
__global__ __launch_bounds__(128) void k3_gather(
    const float* __restrict__ kmem, const float* __restrict__ vmem,
    const int* __restrict__ final_idx, float* __restrict__ out)
{
    const int b = blockIdx.x;
    const int t = threadIdx.x;
    const int idx = final_idx[b];
    const float4* kr = reinterpret_cast<const float4*>(kmem + (size_t)idx * DIM);
    const float4* vr = reinterpret_cast<const float4*>(vmem + (size_t)idx * DIM);
    float4* ok = reinterpret_cast<float4*>(out + (size_t)b * DIM);
    float4* ov = reinterpret_cast<float4*>(out + (size_t)NQ * TOPK * DIM + (size_t)b * DIM);
    ok[t] = kr[t];
    ov[t] = vr[t];
}

extern "C" void kernel_launch(void* const* d_in, const int* in_sizes, int n_in,
                              void* d_out, int out_size, void* d_ws, size_t ws_size,
                              hipStream_t stream)
{
    const float* q    = (const float*)d_in[0];
    const float* kmem = (const float*)d_in[1];
    const float* vmem = (const float*)d_in[2];
    float* out = (float*)d_out;

    // d_out scratch layout (consumed before K3 overwrites everything):
    // [0, 134217728)            bf16 K
    // [134217728, 136314880)    bf16 q
    // [136314880, 169869312)    packed candidates (u32)
    unsigned char* base = (unsigned char*)d_out;
    unsigned short* kbf = (unsigned short*)base;
    unsigned short* qbf = (unsigned short*)(base + (size_t)MSZ * DIM * 2);
    unsigned* cand = (unsigned*)(base + (size_t)MSZ * DIM * 2 + (size_t)NQ * DIM * 2);
    int* final_idx = (int*)d_ws;   // 256 KB, survives the gather

    k0_convert<<<4096, 256, 0, stream>>>(kmem, kbf, MSZ * DIM / 4);
    k0_convert<<<256, 256, 0, stream>>>(q, qbf, NQ * DIM / 4);
    k1_score_select<<<NQ / QT * NCHUNK, 256, 0, stream>>>(qbf, kbf, cand);  // 32768 blocks
    k2_merge_rescore<<<NQ / 4, 256, 0, stream>>>(q, kmem, cand, final_idx);
    k3_gather<<<NQ * TOPK, 128, 0, stream>>>(kmem, vmem, final_idx, out);
}

// Round 4
// 1673.252 us; speedup vs baseline: 1.2709x; 1.0133x over previous
//
#include <hip/hip_runtime.h>
#include <float.h>

#define NQ     2048
#define DIM    512
#define MSZ    131072
#define TOPK   32
#define CH     256
#define NCHUNK (MSZ / CH)        // 512
#define QT     32                // queries per K1 block
#define STRIP  128               // selection strip (rows per lane)
#define NSTRIP (MSZ / STRIP)     // 1024
#define TOPS   6                 // sorted survivors per (query, strip)
#define CPQ    (NSTRIP * TOPS)   // 6144 packed candidates per query
#define NV     (CPQ / 64)        // 96 candidates per K2 lane
#define MERGE  128               // exact-rescore set per query

typedef short  short8 __attribute__((ext_vector_type(8)));
typedef float  f32x4  __attribute__((ext_vector_type(4)));

__device__ __forceinline__ unsigned short f32_to_bf16_rne(float f) {
    union { float f; unsigned u; } v; v.f = f;
    unsigned r = v.u + 0x7FFFu + ((v.u >> 16) & 1u);
    return (unsigned short)(r >> 16);
}
// monotone (order-preserving) u16 transform of bf16 bits
__device__ __forceinline__ unsigned bf16_ordered(unsigned short k) {
    return (k & 0x8000u) ? (unsigned)(unsigned short)~k
                         : (unsigned)(k | 0x8000u);
}
__device__ __forceinline__ unsigned umx(unsigned a, unsigned b) { return a > b ? a : b; }
__device__ __forceinline__ unsigned umn(unsigned a, unsigned b) { return a < b ? a : b; }

// ---------------------------------------------------------------------------
// K0: f32 -> bf16 (RNE) conversion, float4 -> ushort4
// ---------------------------------------------------------------------------
__global__ __launch_bounds__(256) void k0_convert(
    const float* __restrict__ src, unsigned short* __restrict__ dst, int n4)
{
    int i = blockIdx.x * blockDim.x + threadIdx.x;
    const int stride = gridDim.x * blockDim.x;
    const float4* s4 = reinterpret_cast<const float4*>(src);
    ushort4* d4 = reinterpret_cast<ushort4*>(dst);
    for (; i < n4; i += stride) {
        const float4 v = s4[i];
        ushort4 o;
        o.x = f32_to_bf16_rne(v.x); o.y = f32_to_bf16_rne(v.y);
        o.z = f32_to_bf16_rne(v.z); o.w = f32_to_bf16_rne(v.w);
        d4[i] = o;
    }
}

// ---------------------------------------------------------------------------
// K1: bf16 MFMA scoring (32 queries x 256-row chunk) + LANE-PRIVATE top-6
// selection per 128-row strip. No ballots, no SALU counting: each lane of
// wave 0 streams its strip's 128 ordered u16 keys and maintains a sorted-6
// of packed (key<<16 | 127-pos) u32s via a branchless min/max insert chain
// (pure VALU). Previous ballot-search cost ~13 cyc/CU per ballot x 67M
// ballots chipwide = the entire 1.4 ms; this removes all of them.
// Scores are stored to LDS as bf16_ordered keys in an XOR-swizzled layout
// (u32 slot = (rloc>>1) ^ (qloc&31)) so the per-lane strip reads hit
// 2 lanes/bank (free) instead of 64-way conflicts.
// Superset safety: a true global-top-32 row is lost only if >=6 rows with
// higher bf16 key land in its 128-row strip; with ~80 key-superior rows
// spread over 1024 strips, P(any loss) ~ 1.5e-5 over all 2048 queries.
// __launch_bounds__(256,6): 85-VGPR budget, no spill (R2 lesson: (256,8)
// spilled MFMA accumulators -> 3.2 GB scratch traffic).
// ---------------------------------------------------------------------------
__global__ __launch_bounds__(256, 6) void k1_score_select(
    const unsigned short* __restrict__ qbf, const unsigned short* __restrict__ kbf,
    unsigned* __restrict__ cand)
{
    // dispatch slot -> (qt, chunk) with XCD ownership of chunk ranges
    const int s     = blockIdx.x;            // 0..32767
    const int xcd   = s & 7;                 // round-robin XCD assignment
    const int idx   = s >> 3;                // 0..4095 within XCD
    const int qt    = idx & 63;              // fast dim: chunk stays L2-hot
    const int chunk = xcd * (NCHUNK / 8) + (idx >> 6);   // 64 chunks per XCD

    const int tid  = threadIdx.x;
    const int w    = tid >> 6;      // wave 0..3 -> rows w*64..+63
    const int lane = tid & 63;
    const int l15  = lane & 15;
    const int kgrp = lane >> 4;     // k-subgroup 0..3

    __shared__ unsigned sc32[QT][CH / 2];   // 16 KB, XOR-swizzled ordered keys

    // A: Q[qt*32 + mt*16 + l15][k]  row-major, 8 contiguous bf16 per lane
    const unsigned short* Abase = qbf + ((size_t)(qt * QT) + l15) * DIM + kgrp * 8;
    // B: K[chunk*256 + w*64 + nt*16 + l15][k] (B^T pattern)
    const unsigned short* Bbase =
        kbf + ((size_t)chunk * CH + w * 64 + l15) * DIM + kgrp * 8;

    {
        f32x4 acc[2][4];
        #pragma unroll
        for (int mt = 0; mt < 2; ++mt)
            #pragma unroll
            for (int nt = 0; nt < 4; ++nt)
                acc[mt][nt] = (f32x4){0.f, 0.f, 0.f, 0.f};

        #pragma unroll 4
        for (int ks = 0; ks < 16; ++ks) {
            short8 a[2], b[4];
            #pragma unroll
            for (int mt = 0; mt < 2; ++mt)
                a[mt] = *reinterpret_cast<const short8*>(
                    Abase + (size_t)mt * 16 * DIM + ks * 32);
            #pragma unroll
            for (int nt = 0; nt < 4; ++nt)
                b[nt] = *reinterpret_cast<const short8*>(
                    Bbase + (size_t)(nt * 16) * DIM + ks * 32);
            #pragma unroll
            for (int mt = 0; mt < 2; ++mt)
                #pragma unroll
                for (int nt = 0; nt < 4; ++nt)
                    acc[mt][nt] = __builtin_amdgcn_mfma_f32_16x16x32_bf16(
                        a[mt], b[nt], acc[mt][nt], 0, 0, 0);
        }
        // C/D layout: q = mt*16 + kgrp*4 + r, row = w*64 + nt*16 + l15
        // Store ordered key at swizzled u32 slot; both halves of a slot are
        // written by l15-adjacent lanes (same granule, inter-wave disjoint).
        #pragma unroll
        for (int mt = 0; mt < 2; ++mt)
            #pragma unroll
            for (int nt = 0; nt < 4; ++nt)
                #pragma unroll
                for (int r = 0; r < 4; ++r) {
                    const int qloc = mt * 16 + kgrp * 4 + r;
                    const int rloc = w * 64 + nt * 16 + l15;
                    const unsigned short okey =
                        (unsigned short)bf16_ordered(f32_to_bf16_rne(acc[mt][nt][r]));
                    ((unsigned short*)&sc32[qloc][(rloc >> 1) ^ (qloc & 31)])[rloc & 1] = okey;
                }
    }
    __syncthreads();
    if (w != 0) return;   // selection is one wave: 64 lanes = 32q x 2 strips

    // lane = 2q + h: stream 128 keys of query q, strip half h; keep sorted-6
    // of packed (key<<16 | 127-localpos); pure VALU, no cross-lane ops.
    const int q = lane >> 1;
    const int h = lane & 1;
    const unsigned* rowp = sc32[q];
    unsigned s0 = 0, s1 = 0, s2 = 0, s3 = 0, s4 = 0, s5 = 0;
    #pragma unroll 4
    for (int jj = 0; jj < 64; ++jj) {
        const unsigned p = rowp[(h * 64 + jj) ^ (q & 31)];
        const unsigned pos = 127u - 2u * (unsigned)jj;
        const unsigned pk0 = (p << 16) | pos;              // key at localpos 2jj
        const unsigned pk1 = (p & 0xFFFF0000u) | (pos - 1u); // key at 2jj+1
        {   // branchless sorted-6 insert (ascending, s0 = 6th largest)
            const unsigned t0 = umx(s0, pk0), t1 = umx(s1, pk0), t2 = umx(s2, pk0),
                           t3 = umx(s3, pk0), t4 = umx(s4, pk0), t5 = umx(s5, pk0);
            s0 = umn(s1, t0); s1 = umn(s2, t1); s2 = umn(s3, t2);
            s3 = umn(s4, t3); s4 = umn(s5, t4); s5 = t5;
        }
        {
            const unsigned t0 = umx(s0, pk1), t1 = umx(s1, pk1), t2 = umx(s2, pk1),
                           t3 = umx(s3, pk1), t4 = umx(s4, pk1), t5 = umx(s5, pk1);
            s0 = umn(s1, t0); s1 = umn(s2, t1); s2 = umn(s3, t2);
            s3 = umn(s4, t3); s4 = umn(s5, t4); s5 = t5;
        }
    }
    const int qid = qt * QT + q;
    unsigned* base = cand + (size_t)qid * CPQ + (size_t)(chunk * 2 + h) * TOPS;
    base[0] = s5; base[1] = s4; base[2] = s3;
    base[3] = s2; base[4] = s1; base[5] = s0;
}

// ---------------------------------------------------------------------------
// K2: wave per query. Radix-select top-128 of the 6144 packed candidates;
// counting is per-lane VALU + one shfl-xor reduction per round (no ballot
// funnel). Rescore with the BIT-EXACT np chain (ascending single-acc fmaf),
// emit top-32 by (exact score desc, row asc).
// All candidate keys carry bit31 (positive scores), so P starts at 1<<31.
// ---------------------------------------------------------------------------
__global__ __launch_bounds__(256) void k2_merge_rescore(
    const float* __restrict__ q, const float* __restrict__ kmem,
    const unsigned* __restrict__ cand, int* __restrict__ final_idx)
{
    const int w    = threadIdx.x >> 6;
    const int lane = threadIdx.x & 63;
    const int qid  = blockIdx.x * 4 + w;

    __shared__ int   rows_s[4][MERGE];
    __shared__ float scs_s[4][MERGE];

    // load 96 candidates per lane, coalesced uint4
    unsigned v[NV];
    const uint4* cp4 = reinterpret_cast<const uint4*>(cand + (size_t)qid * CPQ);
    #pragma unroll
    for (int j = 0; j < NV / 4; ++j) {
        const uint4 t = cp4[j * 64 + lane];
        v[j * 4 + 0] = t.x; v[j * 4 + 1] = t.y;
        v[j * 4 + 2] = t.z; v[j * 4 + 3] = t.w;
    }
    // P = 128th largest u32; per-lane count + 6-step shfl reduce per round
    unsigned P = 1u << 31;
    for (int b = 30; b >= 0; --b) {
        const unsigned trial = P | (1u << b);
        int cnt = 0;
        #pragma unroll
        for (int j = 0; j < NV; ++j) cnt += (v[j] >= trial);
        #pragma unroll
        for (int m = 1; m < 64; m <<= 1) cnt += __shfl_xor(cnt, m);
        if (cnt >= MERGE) P = trial;
    }
    int gt = 0, eq = 0;
    #pragma unroll
    for (int j = 0; j < NV; ++j) { gt += (v[j] > P); eq += (v[j] == P); }
    int pgt = gt, peq = eq;
    #pragma unroll
    for (int m = 1; m < 64; m <<= 1) {
        const int ag = __shfl_up(pgt, m);
        const int ae = __shfl_up(peq, m);
        if (lane >= m) { pgt += ag; peq += ae; }
    }
    const int totGT = __shfl(pgt, 63);
    pgt -= gt; peq -= eq;
    const int quotaEq = MERGE - totGT;
    {
        int sgt = pgt, seq = peq;
        #pragma unroll
        for (int j = 0; j < NV; ++j) {
            const int off   = (j & ~3) * 64 + lane * 4 + (j & 3); // u32 offset in query's cand block
            const int strip = off / TOPS;                          // const div -> magic mul
            const int row   = strip * STRIP + (STRIP - 1) - (int)(v[j] & 127u);
            if (v[j] > P) {
                rows_s[w][sgt++] = row;
            } else if (v[j] == P) {
                if (seq < quotaEq) rows_s[w][totGT + seq] = row;
                seq++;
            }
        }
    }
    __syncthreads();

    // bit-exact rescore: 2 interleaved ascending fmaf chains per lane
    {
#pragma clang fp contract(off)
        const float4* qr = reinterpret_cast<const float4*>(q + (size_t)qid * DIM);
        const int ra = rows_s[w][lane];
        const int rb = rows_s[w][lane + 64];
        const float4* ka = reinterpret_cast<const float4*>(kmem + (size_t)ra * DIM);
        const float4* kb = reinterpret_cast<const float4*>(kmem + (size_t)rb * DIM);
        float sa = 0.f, sb = 0.f;
        for (int d4 = 0; d4 < DIM / 4; ++d4) {
            const float4 qv = qr[d4];
            const float4 av = ka[d4];
            const float4 bv = kb[d4];
            sa = __builtin_fmaf(qv.x, av.x, sa); sb = __builtin_fmaf(qv.x, bv.x, sb);
            sa = __builtin_fmaf(qv.y, av.y, sa); sb = __builtin_fmaf(qv.y, bv.y, sb);
            sa = __builtin_fmaf(qv.z, av.z, sa); sb = __builtin_fmaf(qv.z, bv.z, sb);
            sa = __builtin_fmaf(qv.w, av.w, sa); sb = __builtin_fmaf(qv.w, bv.w, sb);
        }
        scs_s[w][lane]      = sa;
        scs_s[w][lane + 64] = sb;
    }
    __syncthreads();

    // exact top-32 of 128 by (score desc, row asc)
    float m0 = scs_s[w][lane],      m1 = scs_s[w][lane + 64];
    const int rr0 = rows_s[w][lane], rr1 = rows_s[w][lane + 64];
    for (int sel = 0; sel < TOPK; ++sel) {
        float bs; int bi;
        if (m0 > m1 || (m0 == m1 && rr0 < rr1)) { bs = m0; bi = rr0; }
        else                                    { bs = m1; bi = rr1; }
        #pragma unroll
        for (int m = 1; m < 64; m <<= 1) {
            const float os = __shfl_xor(bs, m);
            const int   oi = __shfl_xor(bi, m);
            if (os > bs || (os == bs && oi < bi)) { bs = os; bi = oi; }
        }
        if (lane == 0) final_idx[qid * TOPK + sel] = bi;
        if (rr0 == bi) m0 = -FLT_MAX;   // rows unique -> removes exactly winner
        if (rr1 == bi) m1 = -FLT_MAX;
    }
}

// ---------------------------------------------------------------------------
// K3: gather K and V rows into the output (k block then v block, flat f32)
// ---------------------------------------------------------------------------
__global__ __launch_bounds__(128) void k3_gather(
    const float* __restrict__ kmem, const float* __restrict__ vmem,
    const int* __restrict__ final_idx, float* __restrict__ out)
{
    const int b = blockIdx.x;
    const int t = threadIdx.x;
    const int idx = final_idx[b];
    const float4* kr = reinterpret_cast<const float4*>(kmem + (size_t)idx * DIM);
    const float4* vr = reinterpret_cast<const float4*>(vmem + (size_t)idx * DIM);
    float4* ok = reinterpret_cast<float4*>(out + (size_t)b * DIM);
    float4* ov = reinterpret_cast<float4*>(out + (size_t)NQ * TOPK * DIM + (size_t)b * DIM);
    ok[t] = kr[t];
    ov[t] = vr[t];
}

extern "C" void kernel_launch(void* const* d_in, const int* in_sizes, int n_in,
                              void* d_out, int out_size, void* d_ws, size_t ws_size,
                              hipStream_t stream)
{
    const float* q    = (const float*)d_in[0];
    const float* kmem = (const float*)d_in[1];
    const float* vmem = (const float*)d_in[2];
    float* out = (float*)d_out;

    // d_out scratch layout (consumed before K3 overwrites everything):
    // [0, 134217728)            bf16 K
    // [134217728, 136314880)    bf16 q
    // [136314880, 186646528)    packed candidates (u32, 2048 x 6144)
    unsigned char* base = (unsigned char*)d_out;
    unsigned short* kbf = (unsigned short*)base;
    unsigned short* qbf = (unsigned short*)(base + (size_t)MSZ * DIM * 2);
    unsigned* cand = (unsigned*)(base + (size_t)MSZ * DIM * 2 + (size_t)NQ * DIM * 2);
    int* final_idx = (int*)d_ws;   // 256 KB, survives the gather

    k0_convert<<<4096, 256, 0, stream>>>(kmem, kbf, MSZ * DIM / 4);
    k0_convert<<<256, 256, 0, stream>>>(q, qbf, NQ * DIM / 4);
    k1_score_select<<<NQ / QT * NCHUNK, 256, 0, stream>>>(qbf, kbf, cand);  // 32768 blocks
    k2_merge_rescore<<<NQ / 4, 256, 0, stream>>>(q, kmem, cand, final_idx);
    k3_gather<<<NQ * TOPK, 128, 0, stream>>>(kmem, vmem, final_idx, out);
}

// Round 5
// 1241.995 us; speedup vs baseline: 1.7122x; 1.3472x over previous
//
#include <hip/hip_runtime.h>
#include <float.h>

#define NQ     2048
#define DIM    512
#define MSZ    131072
#define TOPK   32
#define CH     256
#define NCHUNK (MSZ / CH)        // 512
#define QT     64                // queries per K1 block (B-reuse doubler)
#define STRIP  128               // selection strip (rows per lane)
#define NSTRIP (MSZ / STRIP)     // 1024
#define TOPS   6                 // sorted survivors per (query, strip)
#define CPQ    (NSTRIP * TOPS)   // 6144 packed candidates per query
#define NV     (CPQ / 64)        // 96 candidates per K2 lane
#define MERGE  128               // exact-rescore set per query

typedef short  short8 __attribute__((ext_vector_type(8)));
typedef float  f32x4  __attribute__((ext_vector_type(4)));

__device__ __forceinline__ unsigned short f32_to_bf16_rne(float f) {
    union { float f; unsigned u; } v; v.f = f;
    unsigned r = v.u + 0x7FFFu + ((v.u >> 16) & 1u);
    return (unsigned short)(r >> 16);
}
// monotone (order-preserving) u16 transform of bf16 bits
__device__ __forceinline__ unsigned bf16_ordered(unsigned short k) {
    return (k & 0x8000u) ? (unsigned)(unsigned short)~k
                         : (unsigned)(k | 0x8000u);
}
__device__ __forceinline__ unsigned umx(unsigned a, unsigned b) { return a > b ? a : b; }
__device__ __forceinline__ unsigned umn(unsigned a, unsigned b) { return a < b ? a : b; }

// ---------------------------------------------------------------------------
// K0: f32 -> bf16 (RNE) conversion, float4 -> ushort4
// ---------------------------------------------------------------------------
__global__ __launch_bounds__(256) void k0_convert(
    const float* __restrict__ src, unsigned short* __restrict__ dst, int n4)
{
    int i = blockIdx.x * blockDim.x + threadIdx.x;
    const int stride = gridDim.x * blockDim.x;
    const float4* s4 = reinterpret_cast<const float4*>(src);
    ushort4* d4 = reinterpret_cast<ushort4*>(dst);
    for (; i < n4; i += stride) {
        const float4 v = s4[i];
        ushort4 o;
        o.x = f32_to_bf16_rne(v.x); o.y = f32_to_bf16_rne(v.y);
        o.z = f32_to_bf16_rne(v.z); o.w = f32_to_bf16_rne(v.w);
        d4[i] = o;
    }
}

// ---------------------------------------------------------------------------
// K1: bf16 MFMA scoring (64 queries x 256-row chunk) + lane-private top-6
// selection per 128-row strip.
// WHY QT=64: R1/R3/R4 all ~1430-1470 us across wildly different selection
// schemes and 47-71% occupancy -> K1 is bound by B-tile L2->L1 delivery
// (each block streams CH*DIM*2 B with zero L1 reuse; effective ~10 B/cyc/CU).
// B traffic = (NQ/QT)*128 MB: QT 32->64 halves it (8 GB -> 4 GB).
// Registers: acc 64 AGPR + a[4],b[4] 32 VGPR + addr ~24 => ~120 of the 128
// budget from __launch_bounds__(256,4). NO SPILL (R2 lesson: spill shows as
// WRITE_SIZE explosion).
// Selection: 2 waves (128 lanes = 64 q x 2 strips), branchless sorted-6,
// pure VALU, zero cross-lane ops. Strip geometry/CPQ/K2 unchanged from R4.
// Superset safety: true top-32 row lost only if >=6 higher-bf16-key rows in
// its 128-row strip; ~80 superior rows over 1024 strips -> P ~ 1.5e-5 total.
// XCD-chunking: xcd = s&7 owns 64 contiguous chunks, qt iterates fast ->
// B tile (256 KB) stays L2-resident across its 32 query-tile blocks.
// ---------------------------------------------------------------------------
__global__ __launch_bounds__(256, 4) void k1_score_select(
    const unsigned short* __restrict__ qbf, const unsigned short* __restrict__ kbf,
    unsigned* __restrict__ cand)
{
    // dispatch slot -> (qt, chunk) with XCD ownership of chunk ranges
    const int s     = blockIdx.x;            // 0..16383
    const int xcd   = s & 7;                 // round-robin XCD assignment
    const int idx   = s >> 3;                // 0..2047 within XCD
    const int qt    = idx & 31;              // fast dim: chunk stays L2-hot
    const int chunk = xcd * (NCHUNK / 8) + (idx >> 5);   // 64 chunks per XCD

    const int tid  = threadIdx.x;
    const int w    = tid >> 6;      // wave 0..3 -> rows w*64..+63
    const int lane = tid & 63;
    const int l15  = lane & 15;
    const int kgrp = lane >> 4;     // k-subgroup 0..3

    __shared__ unsigned sc32[QT][CH / 2];   // 32 KB, XOR-swizzled ordered keys

    // A: Q[qt*64 + mt*16 + l15][k]  row-major, 8 contiguous bf16 per lane
    const unsigned short* Abase = qbf + ((size_t)(qt * QT) + l15) * DIM + kgrp * 8;
    // B: K[chunk*256 + w*64 + nt*16 + l15][k] (B^T pattern)
    const unsigned short* Bbase =
        kbf + ((size_t)chunk * CH + w * 64 + l15) * DIM + kgrp * 8;

    {
        f32x4 acc[4][4];
        #pragma unroll
        for (int mt = 0; mt < 4; ++mt)
            #pragma unroll
            for (int nt = 0; nt < 4; ++nt)
                acc[mt][nt] = (f32x4){0.f, 0.f, 0.f, 0.f};

        #pragma unroll 4
        for (int ks = 0; ks < 16; ++ks) {
            short8 a[4], b[4];
            #pragma unroll
            for (int mt = 0; mt < 4; ++mt)
                a[mt] = *reinterpret_cast<const short8*>(
                    Abase + (size_t)mt * 16 * DIM + ks * 32);
            #pragma unroll
            for (int nt = 0; nt < 4; ++nt)
                b[nt] = *reinterpret_cast<const short8*>(
                    Bbase + (size_t)(nt * 16) * DIM + ks * 32);
            #pragma unroll
            for (int mt = 0; mt < 4; ++mt)
                #pragma unroll
                for (int nt = 0; nt < 4; ++nt)
                    acc[mt][nt] = __builtin_amdgcn_mfma_f32_16x16x32_bf16(
                        a[mt], b[nt], acc[mt][nt], 0, 0, 0);
        }
        // C/D layout: q = mt*16 + kgrp*4 + r, row = w*64 + nt*16 + l15
        // Store ordered key at swizzled u32 slot (slot = (rloc>>1)^(qloc&31)).
        #pragma unroll
        for (int mt = 0; mt < 4; ++mt)
            #pragma unroll
            for (int nt = 0; nt < 4; ++nt)
                #pragma unroll
                for (int r = 0; r < 4; ++r) {
                    const int qloc = mt * 16 + kgrp * 4 + r;
                    const int rloc = w * 64 + nt * 16 + l15;
                    const unsigned short okey =
                        (unsigned short)bf16_ordered(f32_to_bf16_rne(acc[mt][nt][r]));
                    ((unsigned short*)&sc32[qloc][(rloc >> 1) ^ (qloc & 31)])[rloc & 1] = okey;
                }
    }
    __syncthreads();
    if (w >= 2) return;   // selection: 2 waves = 128 lanes = 64q x 2 strips

    // g = 2q + h: stream 128 keys of query q, strip half h; keep sorted-6 of
    // packed (key<<16 | 127-localpos); pure VALU, no cross-lane ops.
    const int g = w * 64 + lane;
    const int q = g >> 1;
    const int h = g & 1;
    const unsigned* rowp = sc32[q];
    unsigned s0 = 0, s1 = 0, s2 = 0, s3 = 0, s4 = 0, s5 = 0;
    #pragma unroll 4
    for (int jj = 0; jj < 64; ++jj) {
        const unsigned p = rowp[(h * 64 + jj) ^ (q & 31)];
        const unsigned pos = 127u - 2u * (unsigned)jj;
        const unsigned pk0 = (p << 16) | pos;                // key at localpos 2jj
        const unsigned pk1 = (p & 0xFFFF0000u) | (pos - 1u); // key at 2jj+1
        {   // branchless sorted-6 insert (ascending, s0 = 6th largest)
            const unsigned t0 = umx(s0, pk0), t1 = umx(s1, pk0), t2 = umx(s2, pk0),
                           t3 = umx(s3, pk0), t4 = umx(s4, pk0), t5 = umx(s5, pk0);
            s0 = umn(s1, t0); s1 = umn(s2, t1); s2 = umn(s3, t2);
            s3 = umn(s4, t3); s4 = umn(s5, t4); s5 = t5;
        }
        {
            const unsigned t0 = umx(s0, pk1), t1 = umx(s1, pk1), t2 = umx(s2, pk1),
                           t3 = umx(s3, pk1), t4 = umx(s4, pk1), t5 = umx(s5, pk1);
            s0 = umn(s1, t0); s1 = umn(s2, t1); s2 = umn(s3, t2);
            s3 = umn(s4, t3); s4 = umn(s5, t4); s5 = t5;
        }
    }
    const int qid = qt * QT + q;
    unsigned* base = cand + (size_t)qid * CPQ + (size_t)(chunk * 2 + h) * TOPS;
    base[0] = s5; base[1] = s4; base[2] = s3;
    base[3] = s2; base[4] = s1; base[5] = s0;
}

// ---------------------------------------------------------------------------
// K2: wave per query. Radix-select top-128 of the 6144 packed candidates;
// counting is per-lane VALU + one shfl-xor reduction per round. Rescore with
// the BIT-EXACT np chain (ascending single-acc fmaf), emit top-32 by
// (exact score desc, row asc).
// All candidate keys carry bit31 (positive scores), so P starts at 1<<31.
// ---------------------------------------------------------------------------
__global__ __launch_bounds__(256) void k2_merge_rescore(
    const float* __restrict__ q, const float* __restrict__ kmem,
    const unsigned* __restrict__ cand, int* __restrict__ final_idx)
{
    const int w    = threadIdx.x >> 6;
    const int lane = threadIdx.x & 63;
    const int qid  = blockIdx.x * 4 + w;

    __shared__ int   rows_s[4][MERGE];
    __shared__ float scs_s[4][MERGE];

    // load 96 candidates per lane, coalesced uint4
    unsigned v[NV];
    const uint4* cp4 = reinterpret_cast<const uint4*>(cand + (size_t)qid * CPQ);
    #pragma unroll
    for (int j = 0; j < NV / 4; ++j) {
        const uint4 t = cp4[j * 64 + lane];
        v[j * 4 + 0] = t.x; v[j * 4 + 1] = t.y;
        v[j * 4 + 2] = t.z; v[j * 4 + 3] = t.w;
    }
    // P = 128th largest u32; per-lane count + 6-step shfl reduce per round
    unsigned P = 1u << 31;
    for (int b = 30; b >= 0; --b) {
        const unsigned trial = P | (1u << b);
        int cnt = 0;
        #pragma unroll
        for (int j = 0; j < NV; ++j) cnt += (v[j] >= trial);
        #pragma unroll
        for (int m = 1; m < 64; m <<= 1) cnt += __shfl_xor(cnt, m);
        if (cnt >= MERGE) P = trial;
    }
    int gt = 0, eq = 0;
    #pragma unroll
    for (int j = 0; j < NV; ++j) { gt += (v[j] > P); eq += (v[j] == P); }
    int pgt = gt, peq = eq;
    #pragma unroll
    for (int m = 1; m < 64; m <<= 1) {
        const int ag = __shfl_up(pgt, m);
        const int ae = __shfl_up(peq, m);
        if (lane >= m) { pgt += ag; peq += ae; }
    }
    const int totGT = __shfl(pgt, 63);
    pgt -= gt; peq -= eq;
    const int quotaEq = MERGE - totGT;
    {
        int sgt = pgt, seq = peq;
        #pragma unroll
        for (int j = 0; j < NV; ++j) {
            const int off   = (j & ~3) * 64 + lane * 4 + (j & 3); // u32 offset in query's cand block
            const int strip = off / TOPS;                          // const div -> magic mul
            const int row   = strip * STRIP + (STRIP - 1) - (int)(v[j] & 127u);
            if (v[j] > P) {
                rows_s[w][sgt++] = row;
            } else if (v[j] == P) {
                if (seq < quotaEq) rows_s[w][totGT + seq] = row;
                seq++;
            }
        }
    }
    __syncthreads();

    // bit-exact rescore: 2 interleaved ascending fmaf chains per lane
    {
#pragma clang fp contract(off)
        const float4* qr = reinterpret_cast<const float4*>(q + (size_t)qid * DIM);
        const int ra = rows_s[w][lane];
        const int rb = rows_s[w][lane + 64];
        const float4* ka = reinterpret_cast<const float4*>(kmem + (size_t)ra * DIM);
        const float4* kb = reinterpret_cast<const float4*>(kmem + (size_t)rb * DIM);
        float sa = 0.f, sb = 0.f;
        for (int d4 = 0; d4 < DIM / 4; ++d4) {
            const float4 qv = qr[d4];
            const float4 av = ka[d4];
            const float4 bv = kb[d4];
            sa = __builtin_fmaf(qv.x, av.x, sa); sb = __builtin_fmaf(qv.x, bv.x, sb);
            sa = __builtin_fmaf(qv.y, av.y, sa); sb = __builtin_fmaf(qv.y, bv.y, sb);
            sa = __builtin_fmaf(qv.z, av.z, sa); sb = __builtin_fmaf(qv.z, bv.z, sb);
            sa = __builtin_fmaf(qv.w, av.w, sa); sb = __builtin_fmaf(qv.w, bv.w, sb);
        }
        scs_s[w][lane]      = sa;
        scs_s[w][lane + 64] = sb;
    }
    __syncthreads();

    // exact top-32 of 128 by (score desc, row asc)
    float m0 = scs_s[w][lane],      m1 = scs_s[w][lane + 64];
    const int rr0 = rows_s[w][lane], rr1 = rows_s[w][lane + 64];
    for (int sel = 0; sel < TOPK; ++sel) {
        float bs; int bi;
        if (m0 > m1 || (m0 == m1 && rr0 < rr1)) { bs = m0; bi = rr0; }
        else                                    { bs = m1; bi = rr1; }
        #pragma unroll
        for (int m = 1; m < 64; m <<= 1) {
            const float os = __shfl_xor(bs, m);
            const int   oi = __shfl_xor(bi, m);
            if (os > bs || (os == bs && oi < bi)) { bs = os; bi = oi; }
        }
        if (lane == 0) final_idx[qid * TOPK + sel] = bi;
        if (rr0 == bi) m0 = -FLT_MAX;   // rows unique -> removes exactly winner
        if (rr1 == bi) m1 = -FLT_MAX;
    }
}

// ---------------------------------------------------------------------------
// K3: gather K and V rows into the output (k block then v block, flat f32)
// ---------------------------------------------------------------------------
__global__ __launch_bounds__(128) void k3_gather(
    const float* __restrict__ kmem, const float* __restrict__ vmem,
    const int* __restrict__ final_idx, float* __restrict__ out)
{
    const int b = blockIdx.x;
    const int t = threadIdx.x;
    const int idx = final_idx[b];
    const float4* kr = reinterpret_cast<const float4*>(kmem + (size_t)idx * DIM);
    const float4* vr = reinterpret_cast<const float4*>(vmem + (size_t)idx * DIM);
    float4* ok = reinterpret_cast<float4*>(out + (size_t)b * DIM);
    float4* ov = reinterpret_cast<float4*>(out + (size_t)NQ * TOPK * DIM + (size_t)b * DIM);
    ok[t] = kr[t];
    ov[t] = vr[t];
}

extern "C" void kernel_launch(void* const* d_in, const int* in_sizes, int n_in,
                              void* d_out, int out_size, void* d_ws, size_t ws_size,
                              hipStream_t stream)
{
    const float* q    = (const float*)d_in[0];
    const float* kmem = (const float*)d_in[1];
    const float* vmem = (const float*)d_in[2];
    float* out = (float*)d_out;

    // d_out scratch layout (consumed before K3 overwrites everything):
    // [0, 134217728)            bf16 K
    // [134217728, 136314880)    bf16 q
    // [136314880, 186646528)    packed candidates (u32, 2048 x 6144)
    unsigned char* base = (unsigned char*)d_out;
    unsigned short* kbf = (unsigned short*)base;
    unsigned short* qbf = (unsigned short*)(base + (size_t)MSZ * DIM * 2);
    unsigned* cand = (unsigned*)(base + (size_t)MSZ * DIM * 2 + (size_t)NQ * DIM * 2);
    int* final_idx = (int*)d_ws;   // 256 KB, survives the gather

    k0_convert<<<4096, 256, 0, stream>>>(kmem, kbf, MSZ * DIM / 4);
    k0_convert<<<256, 256, 0, stream>>>(q, qbf, NQ * DIM / 4);
    k1_score_select<<<NQ / QT * NCHUNK, 256, 0, stream>>>(qbf, kbf, cand);  // 16384 blocks
    k2_merge_rescore<<<NQ / 4, 256, 0, stream>>>(q, kmem, cand, final_idx);
    k3_gather<<<NQ * TOPK, 128, 0, stream>>>(kmem, vmem, final_idx, out);
}

// Round 6
// 722.376 us; speedup vs baseline: 2.9438x; 1.7193x over previous
//
#include <hip/hip_runtime.h>
#include <float.h>

#define NQ     2048
#define DIM    512
#define MSZ    131072
#define TOPK   32
#define QT     128               // queries per K1 block (BM)
#define BN     128               // k-rows per K1 block
#define BK     64                // K-step
#define STRIP  128               // selection strip = one block's BN range
#define NSTRIP (MSZ / STRIP)     // 1024
#define TOPS   6                 // sorted survivors per (query, strip)
#define CPQ    (NSTRIP * TOPS)   // 6144 packed candidates per query
#define NV     (CPQ / 64)        // 96 candidates per K2 lane
#define MERGE  128               // exact-rescore set per query

typedef short  short8 __attribute__((ext_vector_type(8)));
typedef float  f32x4  __attribute__((ext_vector_type(4)));

__device__ __forceinline__ unsigned short f32_to_bf16_rne(float f) {
    union { float f; unsigned u; } v; v.f = f;
    unsigned r = v.u + 0x7FFFu + ((v.u >> 16) & 1u);
    return (unsigned short)(r >> 16);
}
// monotone (order-preserving) u16 transform of bf16 bits
__device__ __forceinline__ unsigned bf16_ordered(unsigned short k) {
    return (k & 0x8000u) ? (unsigned)(unsigned short)~k
                         : (unsigned)(k | 0x8000u);
}
__device__ __forceinline__ unsigned umx(unsigned a, unsigned b) { return a > b ? a : b; }
__device__ __forceinline__ unsigned umn(unsigned a, unsigned b) { return a < b ? a : b; }

// async global->LDS, 16 B per lane. LDS dest is wave-uniform base + lane*16;
// global src is per-lane (this is how the swizzle is applied on the source).
__device__ __forceinline__ void gload16(const void* g, void* l) {
    __builtin_amdgcn_global_load_lds(
        (const __attribute__((address_space(1))) unsigned int*)g,
        (__attribute__((address_space(3))) unsigned int*)l, 16, 0, 0);
}

// ---------------------------------------------------------------------------
// K0: f32 -> bf16 (RNE) conversion, float4 -> ushort4
// ---------------------------------------------------------------------------
__global__ __launch_bounds__(256) void k0_convert(
    const float* __restrict__ src, unsigned short* __restrict__ dst, int n4)
{
    int i = blockIdx.x * blockDim.x + threadIdx.x;
    const int stride = gridDim.x * blockDim.x;
    const float4* s4 = reinterpret_cast<const float4*>(src);
    ushort4* d4 = reinterpret_cast<ushort4*>(dst);
    for (; i < n4; i += stride) {
        const float4 v = s4[i];
        ushort4 o;
        o.x = f32_to_bf16_rne(v.x); o.y = f32_to_bf16_rne(v.y);
        o.z = f32_to_bf16_rne(v.z); o.w = f32_to_bf16_rne(v.w);
        d4[i] = o;
    }
}

// ---------------------------------------------------------------------------
// K1: LDS-staged MFMA GEMM tile (128 queries x 128 rows, BK=64, m97-style
// 2-barrier loop with width-16 global_load_lds) + lane-private top-6
// selection per (query, 128-row strip).
// WHY: R5 measured the per-wave global->VGPR path saturated at ~13 B/cyc/CU
// (8 GB over 980 us). global_load_lds + block-wide LDS reuse sustains ~50
// B/cyc/CU (m97 evidence: 874 TF). Traffic: A 2 GB + B 2 GB, each byte
// loaded once per block, reused 128x from LDS.
// LDS swizzle (G4 + rule #21, both-sides-or-neither): linear [row][64] bf16
// tiles are a 16-way read conflict (row stride 128 B). Store column-byte
// cb XOR'd with (row&7)<<4. gload_lds writes linearly, so the SOURCE column
// is inverse-swizzled per lane: cb_src = 16*((lane&7)^(row&7)); ds_read
// applies the same XOR. Involution verified: read of logical col c at row r
// uses cb = c ^ ((r&7)<<4), which holds logical[r][c].
// Registers: acc 64 + 8 live frags 32 + addr ~30 -> launch_bounds(256,3)
// (170 budget, no spill; R2 lesson: spill = WRITE_SIZE explosion).
// Selection: block's 128 rows = exactly one strip -> per-q top-6 sorted
// insert (pure VALU), threads 0..127, one task each. CPQ/K2 unchanged.
// Superset safety: unchanged from R4/R5 (top-6 of 128-row strip, ~1.5e-5).
// XCD-chunking: xcd = s&7 owns 128 contiguous bn values; qt iterates fast
// -> B tile (128 KB) L2-resident across its 16 query-tile blocks.
// ---------------------------------------------------------------------------
__global__ __launch_bounds__(256, 3) void k1_score_select(
    const unsigned short* __restrict__ qbf, const unsigned short* __restrict__ kbf,
    unsigned* __restrict__ cand)
{
    const int s   = blockIdx.x;              // 0..16383
    const int xcd = s & 7;
    const int idx = s >> 3;                  // 0..2047 within XCD
    const int qt  = idx & 15;                // fast dim: B tile stays L2-hot
    const int bn  = xcd * (NSTRIP / 8) + (idx >> 4);   // 128 strips per XCD

    const int tid  = threadIdx.x;
    const int w    = tid >> 6;      // wave 0..3, 2x2 grid
    const int lane = tid & 63;
    const int l15  = lane & 15;
    const int kgrp = lane >> 4;     // k-subgroup 0..3
    const int wq   = w >> 1;        // wave's query-quadrant (0..1)
    const int wr   = w & 1;         // wave's row-quadrant  (0..1)
    const int l8   = lane >> 3;     // staging: row-within-8
    const int lc   = lane & 7;      // staging: col-16B-within-row

    __shared__ char lds[32768];     // A tile 16 KB | B tile 16 KB; reused for scores
    char* ldsA = lds;
    char* ldsB = lds + 16384;

    const char* gA = (const char*)qbf;   // bf16 Q, row stride 1024 B
    const char* gB = (const char*)kbf;   // bf16 K, row stride 1024 B

    f32x4 acc[4][4];
    #pragma unroll
    for (int mt = 0; mt < 4; ++mt)
        #pragma unroll
        for (int nt = 0; nt < 4; ++nt)
            acc[mt][nt] = (f32x4){0.f, 0.f, 0.f, 0.f};

    for (int kk = 0; kk < DIM / BK; ++kk) {
        // stage A and B tiles: per wave 4 issues each; LDS linear, source
        // column inverse-swizzled so ds_read's XOR sees logical data.
        #pragma unroll
        for (int t = 0; t < 4; ++t) {
            const int row = w * 32 + t * 8 + l8;
            const int cb  = 16 * (lc ^ (row & 7));
            gload16(gA + ((size_t)(qt * QT + row) << 10) + kk * (BK * 2) + cb,
                    ldsA + (w * 4 + t) * 1024);
            gload16(gB + ((size_t)(bn * BN + row) << 10) + kk * (BK * 2) + cb,
                    ldsB + (w * 4 + t) * 1024);
        }
        __syncthreads();   // drains vmcnt: tiles visible

        #pragma unroll
        for (int ks = 0; ks < 2; ++ks) {
            short8 a[4], b[4];
            #pragma unroll
            for (int mt = 0; mt < 4; ++mt) {
                const int r = wq * 64 + mt * 16 + l15;
                a[mt] = *reinterpret_cast<const short8*>(
                    ldsA + r * 128 + ((ks * 64 + kgrp * 16) ^ ((r & 7) << 4)));
            }
            #pragma unroll
            for (int nt = 0; nt < 4; ++nt) {
                const int r = wr * 64 + nt * 16 + l15;
                b[nt] = *reinterpret_cast<const short8*>(
                    ldsB + r * 128 + ((ks * 64 + kgrp * 16) ^ ((r & 7) << 4)));
            }
            #pragma unroll
            for (int mt = 0; mt < 4; ++mt)
                #pragma unroll
                for (int nt = 0; nt < 4; ++nt)
                    acc[mt][nt] = __builtin_amdgcn_mfma_f32_16x16x32_bf16(
                        a[mt], b[nt], acc[mt][nt], 0, 0, 0);
        }
        __syncthreads();   // protect LDS from next stage overwrite
    }

    // scores -> LDS (overlaying the dead stage buffers), swizzled u32 slots
    unsigned* sc32 = reinterpret_cast<unsigned*>(lds);   // [128 q][64 slots]
    #pragma unroll
    for (int mt = 0; mt < 4; ++mt)
        #pragma unroll
        for (int nt = 0; nt < 4; ++nt)
            #pragma unroll
            for (int r = 0; r < 4; ++r) {
                const int q  = wq * 64 + mt * 16 + kgrp * 4 + r;
                const int rl = wr * 64 + nt * 16 + l15;
                const unsigned short okey =
                    (unsigned short)bf16_ordered(f32_to_bf16_rne(acc[mt][nt][r]));
                ((unsigned short*)&sc32[q * 64 + ((rl >> 1) ^ (q & 31))])[rl & 1] = okey;
            }
    __syncthreads();
    if (tid >= QT) return;   // selection: 128 threads, one (q, strip) each

    const int q = tid;
    const unsigned* rowp = sc32 + q * 64;
    unsigned s0 = 0, s1 = 0, s2 = 0, s3 = 0, s4 = 0, s5 = 0;
    #pragma unroll 4
    for (int jj = 0; jj < 64; ++jj) {
        const unsigned p = rowp[jj ^ (q & 31)];
        const unsigned pos = 127u - 2u * (unsigned)jj;
        const unsigned pk0 = (p << 16) | pos;                // key at local row 2jj
        const unsigned pk1 = (p & 0xFFFF0000u) | (pos - 1u); // key at 2jj+1
        {   // branchless sorted-6 insert (ascending, s0 = 6th largest)
            const unsigned t0 = umx(s0, pk0), t1 = umx(s1, pk0), t2 = umx(s2, pk0),
                           t3 = umx(s3, pk0), t4 = umx(s4, pk0), t5 = umx(s5, pk0);
            s0 = umn(s1, t0); s1 = umn(s2, t1); s2 = umn(s3, t2);
            s3 = umn(s4, t3); s4 = umn(s5, t4); s5 = t5;
        }
        {
            const unsigned t0 = umx(s0, pk1), t1 = umx(s1, pk1), t2 = umx(s2, pk1),
                           t3 = umx(s3, pk1), t4 = umx(s4, pk1), t5 = umx(s5, pk1);
            s0 = umn(s1, t0); s1 = umn(s2, t1); s2 = umn(s3, t2);
            s3 = umn(s4, t3); s4 = umn(s5, t4); s5 = t5;
        }
    }
    const int qid = qt * QT + q;
    unsigned* base = cand + (size_t)qid * CPQ + (size_t)bn * TOPS;
    base[0] = s5; base[1] = s4; base[2] = s3;
    base[3] = s2; base[4] = s1; base[5] = s0;
}

// ---------------------------------------------------------------------------
// K2: wave per query. Radix-select top-128 of the 6144 packed candidates;
// counting is per-lane VALU + one shfl-xor reduction per round. Rescore with
// the BIT-EXACT np chain (ascending single-acc fmaf), emit top-32 by
// (exact score desc, row asc).
// All candidate keys carry bit31 (positive scores), so P starts at 1<<31.
// ---------------------------------------------------------------------------
__global__ __launch_bounds__(256) void k2_merge_rescore(
    const float* __restrict__ q, const float* __restrict__ kmem,
    const unsigned* __restrict__ cand, int* __restrict__ final_idx)
{
    const int w    = threadIdx.x >> 6;
    const int lane = threadIdx.x & 63;
    const int qid  = blockIdx.x * 4 + w;

    __shared__ int   rows_s[4][MERGE];
    __shared__ float scs_s[4][MERGE];

    // load 96 candidates per lane, coalesced uint4
    unsigned v[NV];
    const uint4* cp4 = reinterpret_cast<const uint4*>(cand + (size_t)qid * CPQ);
    #pragma unroll
    for (int j = 0; j < NV / 4; ++j) {
        const uint4 t = cp4[j * 64 + lane];
        v[j * 4 + 0] = t.x; v[j * 4 + 1] = t.y;
        v[j * 4 + 2] = t.z; v[j * 4 + 3] = t.w;
    }
    // P = 128th largest u32; per-lane count + 6-step shfl reduce per round
    unsigned P = 1u << 31;
    for (int b = 30; b >= 0; --b) {
        const unsigned trial = P | (1u << b);
        int cnt = 0;
        #pragma unroll
        for (int j = 0; j < NV; ++j) cnt += (v[j] >= trial);
        #pragma unroll
        for (int m = 1; m < 64; m <<= 1) cnt += __shfl_xor(cnt, m);
        if (cnt >= MERGE) P = trial;
    }
    int gt = 0, eq = 0;
    #pragma unroll
    for (int j = 0; j < NV; ++j) { gt += (v[j] > P); eq += (v[j] == P); }
    int pgt = gt, peq = eq;
    #pragma unroll
    for (int m = 1; m < 64; m <<= 1) {
        const int ag = __shfl_up(pgt, m);
        const int ae = __shfl_up(peq, m);
        if (lane >= m) { pgt += ag; peq += ae; }
    }
    const int totGT = __shfl(pgt, 63);
    pgt -= gt; peq -= eq;
    const int quotaEq = MERGE - totGT;
    {
        int sgt = pgt, seq = peq;
        #pragma unroll
        for (int j = 0; j < NV; ++j) {
            const int off   = (j & ~3) * 64 + lane * 4 + (j & 3); // u32 offset in query's cand block
            const int strip = off / TOPS;                          // const div -> magic mul
            const int row   = strip * STRIP + (STRIP - 1) - (int)(v[j] & 127u);
            if (v[j] > P) {
                rows_s[w][sgt++] = row;
            } else if (v[j] == P) {
                if (seq < quotaEq) rows_s[w][totGT + seq] = row;
                seq++;
            }
        }
    }
    __syncthreads();

    // bit-exact rescore: 2 interleaved ascending fmaf chains per lane
    {
#pragma clang fp contract(off)
        const float4* qr = reinterpret_cast<const float4*>(q + (size_t)qid * DIM);
        const int ra = rows_s[w][lane];
        const int rb = rows_s[w][lane + 64];
        const float4* ka = reinterpret_cast<const float4*>(kmem + (size_t)ra * DIM);
        const float4* kb = reinterpret_cast<const float4*>(kmem + (size_t)rb * DIM);
        float sa = 0.f, sb = 0.f;
        for (int d4 = 0; d4 < DIM / 4; ++d4) {
            const float4 qv = qr[d4];
            const float4 av = ka[d4];
            const float4 bv = kb[d4];
            sa = __builtin_fmaf(qv.x, av.x, sa); sb = __builtin_fmaf(qv.x, bv.x, sb);
            sa = __builtin_fmaf(qv.y, av.y, sa); sb = __builtin_fmaf(qv.y, bv.y, sb);
            sa = __builtin_fmaf(qv.z, av.z, sa); sb = __builtin_fmaf(qv.z, bv.z, sb);
            sa = __builtin_fmaf(qv.w, av.w, sa); sb = __builtin_fmaf(qv.w, bv.w, sb);
        }
        scs_s[w][lane]      = sa;
        scs_s[w][lane + 64] = sb;
    }
    __syncthreads();

    // exact top-32 of 128 by (score desc, row asc)
    float m0 = scs_s[w][lane],      m1 = scs_s[w][lane + 64];
    const int rr0 = rows_s[w][lane], rr1 = rows_s[w][lane + 64];
    for (int sel = 0; sel < TOPK; ++sel) {
        float bs; int bi;
        if (m0 > m1 || (m0 == m1 && rr0 < rr1)) { bs = m0; bi = rr0; }
        else                                    { bs = m1; bi = rr1; }
        #pragma unroll
        for (int m = 1; m < 64; m <<= 1) {
            const float os = __shfl_xor(bs, m);
            const int   oi = __shfl_xor(bi, m);
            if (os > bs || (os == bs && oi < bi)) { bs = os; bi = oi; }
        }
        if (lane == 0) final_idx[qid * TOPK + sel] = bi;
        if (rr0 == bi) m0 = -FLT_MAX;   // rows unique -> removes exactly winner
        if (rr1 == bi) m1 = -FLT_MAX;
    }
}

// ---------------------------------------------------------------------------
// K3: gather K and V rows into the output (k block then v block, flat f32)
// ---------------------------------------------------------------------------
__global__ __launch_bounds__(128) void k3_gather(
    const float* __restrict__ kmem, const float* __restrict__ vmem,
    const int* __restrict__ final_idx, float* __restrict__ out)
{
    const int b = blockIdx.x;
    const int t = threadIdx.x;
    const int idx = final_idx[b];
    const float4* kr = reinterpret_cast<const float4*>(kmem + (size_t)idx * DIM);
    const float4* vr = reinterpret_cast<const float4*>(vmem + (size_t)idx * DIM);
    float4* ok = reinterpret_cast<float4*>(out + (size_t)b * DIM);
    float4* ov = reinterpret_cast<float4*>(out + (size_t)NQ * TOPK * DIM + (size_t)b * DIM);
    ok[t] = kr[t];
    ov[t] = vr[t];
}

extern "C" void kernel_launch(void* const* d_in, const int* in_sizes, int n_in,
                              void* d_out, int out_size, void* d_ws, size_t ws_size,
                              hipStream_t stream)
{
    const float* q    = (const float*)d_in[0];
    const float* kmem = (const float*)d_in[1];
    const float* vmem = (const float*)d_in[2];
    float* out = (float*)d_out;

    // d_out scratch layout (consumed before K3 overwrites everything):
    // [0, 134217728)            bf16 K
    // [134217728, 136314880)    bf16 q
    // [136314880, 186646528)    packed candidates (u32, 2048 x 6144)
    unsigned char* base = (unsigned char*)d_out;
    unsigned short* kbf = (unsigned short*)base;
    unsigned short* qbf = (unsigned short*)(base + (size_t)MSZ * DIM * 2);
    unsigned* cand = (unsigned*)(base + (size_t)MSZ * DIM * 2 + (size_t)NQ * DIM * 2);
    int* final_idx = (int*)d_ws;   // 256 KB, survives the gather

    k0_convert<<<4096, 256, 0, stream>>>(kmem, kbf, MSZ * DIM / 4);
    k0_convert<<<256, 256, 0, stream>>>(q, qbf, NQ * DIM / 4);
    k1_score_select<<<(NQ / QT) * NSTRIP, 256, 0, stream>>>(qbf, kbf, cand);  // 16384 blocks
    k2_merge_rescore<<<NQ / 4, 256, 0, stream>>>(q, kmem, cand, final_idx);
    k3_gather<<<NQ * TOPK, 128, 0, stream>>>(kmem, vmem, final_idx, out);
}

// Round 7
// 717.778 us; speedup vs baseline: 2.9627x; 1.0064x over previous
//
#include <hip/hip_runtime.h>
#include <float.h>

#define NQ     2048
#define DIM    512
#define MSZ    131072
#define TOPK   32
#define QT     128               // queries per K1 block (BM)
#define BN     128               // k-rows per K1 block
#define BK     32                // K-step (double-buffered)
#define STRIP  128               // selection strip = one block's BN range
#define NSTRIP (MSZ / STRIP)     // 1024
#define TOPS   6                 // sorted survivors per (query, strip)
#define CPQ    (NSTRIP * TOPS)   // 6144 packed candidates per query
#define NV     (CPQ / 64)        // 96 candidates per K2 lane
#define MERGE  128               // exact-rescore set per query

typedef short  short8 __attribute__((ext_vector_type(8)));
typedef float  f32x4  __attribute__((ext_vector_type(4)));

__device__ __forceinline__ unsigned short f32_to_bf16_rne(float f) {
    union { float f; unsigned u; } v; v.f = f;
    unsigned r = v.u + 0x7FFFu + ((v.u >> 16) & 1u);
    return (unsigned short)(r >> 16);
}
// monotone (order-preserving) u16 transform of bf16 bits
__device__ __forceinline__ unsigned bf16_ordered(unsigned short k) {
    return (k & 0x8000u) ? (unsigned)(unsigned short)~k
                         : (unsigned)(k | 0x8000u);
}
__device__ __forceinline__ unsigned umx(unsigned a, unsigned b) { return a > b ? a : b; }
__device__ __forceinline__ unsigned umn(unsigned a, unsigned b) { return a < b ? a : b; }

// async global->LDS, 16 B per lane. LDS dest is wave-uniform base + lane*16;
// global src is per-lane (swizzle is applied on the source address).
__device__ __forceinline__ void gload16(const void* g, void* l) {
    __builtin_amdgcn_global_load_lds(
        (const __attribute__((address_space(1))) unsigned int*)g,
        (__attribute__((address_space(3))) unsigned int*)l, 16, 0, 0);
}

// branchless sorted-6 insert: keeps s0<=s1<=...<=s5 (s5 = max, s0 = 6th largest)
#define INS6(pk)                                                             \
    {                                                                        \
        const unsigned t0 = umx(s0, pk), t1 = umx(s1, pk), t2 = umx(s2, pk), \
                       t3 = umx(s3, pk), t4 = umx(s4, pk), t5 = umx(s5, pk); \
        s0 = umn(s1, t0); s1 = umn(s2, t1); s2 = umn(s3, t2);                \
        s3 = umn(s4, t3); s4 = umn(s5, t4); s5 = t5;                         \
    }

// ---------------------------------------------------------------------------
// K0: f32 -> bf16 (RNE) conversion, float4 -> ushort4
// ---------------------------------------------------------------------------
__global__ __launch_bounds__(256) void k0_convert(
    const float* __restrict__ src, unsigned short* __restrict__ dst, int n4)
{
    int i = blockIdx.x * blockDim.x + threadIdx.x;
    const int stride = gridDim.x * blockDim.x;
    const float4* s4 = reinterpret_cast<const float4*>(src);
    ushort4* d4 = reinterpret_cast<ushort4*>(dst);
    for (; i < n4; i += stride) {
        const float4 v = s4[i];
        ushort4 o;
        o.x = f32_to_bf16_rne(v.x); o.y = f32_to_bf16_rne(v.y);
        o.z = f32_to_bf16_rne(v.z); o.w = f32_to_bf16_rne(v.w);
        d4[i] = o;
    }
}

// ---------------------------------------------------------------------------
// K1: double-buffered LDS-staged MFMA GEMM (128q x 128rows, BK=32) with
// issue-early/drain-late prefetch (T3 minimum recipe): each iter issues the
// NEXT tile's global_load_lds before computing the CURRENT buffer, and the
// single end-of-iter __syncthreads drains loads that had the whole MFMA
// phase in flight. R6 (stage->barrier->compute->barrier) exposed full L2
// latency per tile; per-block pipe floors are ~2 us each on 4 different
// pipes, so overlap is the remaining lever.
// LDS swizzle for 64-B rows (both-sides-or-neither, rule #21): physical
// 16B-slot = kgrp ^ ((row>>1)&3); inverse applied on the gload SOURCE,
// same XOR on ds_read -> 2 lanes/bank (free). Involution verified.
// Selection: 256 threads, each does sorted-6 over one 64-key half-strip
// (pure VALU, no cross-lane); thread q<128 then inserts the other half's 6
// from LDS (stride-9 pad, conflict-free) -> exact strip top-6. CPQ/K2
// unchanged. Superset safety unchanged (top-6 of 128-row strip, ~1.5e-5).
// Registers: acc 64 + frags 32 + addr -> (256,3) = 170 budget, no spill
// (R2 lesson: spill = WRITE_SIZE explosion).
// XCD-chunking: xcd = s&7 owns 128 contiguous strips; qt fast -> B tile
// L2-resident across its 16 query-tile blocks.
// ---------------------------------------------------------------------------
__global__ __launch_bounds__(256, 3) void k1_score_select(
    const unsigned short* __restrict__ qbf, const unsigned short* __restrict__ kbf,
    unsigned* __restrict__ cand)
{
    const int s   = blockIdx.x;              // 0..16383
    const int xcd = s & 7;
    const int idx = s >> 3;                  // 0..2047 within XCD
    const int qt  = idx & 15;                // fast dim: B tile stays L2-hot
    const int bn  = xcd * (NSTRIP / 8) + (idx >> 4);   // 128 strips per XCD

    const int tid  = threadIdx.x;
    const int w    = tid >> 6;      // wave 0..3, 2x2 grid
    const int lane = tid & 63;
    const int l15  = lane & 15;
    const int kgrp = lane >> 4;     // k-subgroup 0..3 (16B slot of the 64B row)
    const int wq   = w >> 1;        // wave's query-quadrant (0..1)
    const int wr   = w & 1;         // wave's row-quadrant  (0..1)
    const int srow = lane >> 2;     // staging: row within 16-row group
    const int sslt = lane & 3;      // staging: physical 16B slot

    // [0,16384)      bufA[2][128 rows][64 B]
    // [16384,32768)  bufB[2][128 rows][64 B]
    // scores overlay [0,32768) after the loop; selbuf u32[256][9] above
    __shared__ __align__(16) char lds[32768 + 256 * 9 * 4];

    const char* gA = (const char*)qbf;   // bf16 Q, row stride 1024 B
    const char* gB = (const char*)kbf;   // bf16 K, row stride 1024 B

    f32x4 acc[4][4];
    #pragma unroll
    for (int mt = 0; mt < 4; ++mt)
        #pragma unroll
        for (int nt = 0; nt < 4; ++nt)
            acc[mt][nt] = (f32x4){0.f, 0.f, 0.f, 0.f};

    // stage tile kkv into buffer bsel: per wave 2 issues A + 2 issues B.
    // dest is linear (rbase rows x 64 B); source K-slot inverse-swizzled.
#define STAGE(kkv, bsel)                                                      \
    {                                                                         \
        _Pragma("unroll")                                                     \
        for (int t = 0; t < 2; ++t) {                                         \
            const int rbase = w * 32 + t * 16;                                \
            const int r = rbase + srow;                                       \
            const int ksl = sslt ^ ((r >> 1) & 3);                            \
            gload16(gA + ((size_t)(qt * QT + r) << 10) + (kkv) * 64 + ksl * 16, \
                    lds + (bsel) * 8192 + rbase * 64);                        \
            gload16(gB + ((size_t)(bn * BN + r) << 10) + (kkv) * 64 + ksl * 16, \
                    lds + 16384 + (bsel) * 8192 + rbase * 64);                \
        }                                                                     \
    }

    STAGE(0, 0);
    __syncthreads();

    #pragma unroll 2
    for (int kk = 0; kk < DIM / BK; ++kk) {
        const int cur = kk & 1;
        if (kk < DIM / BK - 1) STAGE(kk + 1, cur ^ 1);   // issue-early

        const char* bA = lds + cur * 8192;
        const char* bB = lds + 16384 + cur * 8192;
        short8 a[4], b[4];
        #pragma unroll
        for (int mt = 0; mt < 4; ++mt) {
            const int r = wq * 64 + mt * 16 + l15;
            a[mt] = *reinterpret_cast<const short8*>(
                bA + r * 64 + ((kgrp ^ ((r >> 1) & 3)) * 16));
        }
        #pragma unroll
        for (int nt = 0; nt < 4; ++nt) {
            const int r = wr * 64 + nt * 16 + l15;
            b[nt] = *reinterpret_cast<const short8*>(
                bB + r * 64 + ((kgrp ^ ((r >> 1) & 3)) * 16));
        }
        #pragma unroll
        for (int mt = 0; mt < 4; ++mt)
            #pragma unroll
            for (int nt = 0; nt < 4; ++nt)
                acc[mt][nt] = __builtin_amdgcn_mfma_f32_16x16x32_bf16(
                    a[mt], b[nt], acc[mt][nt], 0, 0, 0);

        __syncthreads();   // drain-late: prefetched loads flew during MFMA
    }

    // scores -> LDS (overlaying the dead stage buffers), swizzled u32 slots
    unsigned* sc32 = reinterpret_cast<unsigned*>(lds);   // [128 q][64 slots]
    #pragma unroll
    for (int mt = 0; mt < 4; ++mt)
        #pragma unroll
        for (int nt = 0; nt < 4; ++nt)
            #pragma unroll
            for (int r = 0; r < 4; ++r) {
                const int q  = wq * 64 + mt * 16 + kgrp * 4 + r;
                const int rl = wr * 64 + nt * 16 + l15;
                const unsigned short okey =
                    (unsigned short)bf16_ordered(f32_to_bf16_rne(acc[mt][nt][r]));
                ((unsigned short*)&sc32[q * 64 + ((rl >> 1) ^ (q & 31))])[rl & 1] = okey;
            }
    __syncthreads();

    // selection pass 1: 256 threads, sorted-6 over one 64-key half-strip
    unsigned* selb = reinterpret_cast<unsigned*>(lds + 32768);  // [256][9]
    const int q = tid & 127;
    const int h = tid >> 7;
    {
        const unsigned* rowp = sc32 + q * 64;
        unsigned s0 = 0, s1 = 0, s2 = 0, s3 = 0, s4 = 0, s5 = 0;
        #pragma unroll 4
        for (int u = 0; u < 32; ++u) {
            const int jj = h * 32 + u;
            const unsigned p = rowp[jj ^ (q & 31)];
            const unsigned pos = 127u - 2u * (unsigned)jj;
            const unsigned pk0 = (p << 16) | pos;                // local row 2jj
            const unsigned pk1 = (p & 0xFFFF0000u) | (pos - 1u); // local row 2jj+1
            INS6(pk0);
            INS6(pk1);
        }
        unsigned* o = selb + tid * 9;
        o[0] = s0; o[1] = s1; o[2] = s2; o[3] = s3; o[4] = s4; o[5] = s5;
    }
    __syncthreads();
    if (tid >= QT) return;

    // selection pass 2: thread q merges its half (reloaded) + other half
    {
        const unsigned* mine  = selb + q * 9;
        const unsigned* other = selb + (q + 128) * 9;
        unsigned s0 = mine[0], s1 = mine[1], s2 = mine[2],
                 s3 = mine[3], s4 = mine[4], s5 = mine[5];
        #pragma unroll
        for (int u = 0; u < 6; ++u) {
            const unsigned pk = other[u];
            INS6(pk);
        }
        const int qid = qt * QT + q;
        unsigned* base = cand + (size_t)qid * CPQ + (size_t)bn * TOPS;
        base[0] = s5; base[1] = s4; base[2] = s3;
        base[3] = s2; base[4] = s1; base[5] = s0;
    }
#undef STAGE
}

// ---------------------------------------------------------------------------
// K2: wave per query. Radix-select top-128 of the 6144 packed candidates;
// counting is per-lane VALU + one shfl-xor reduction per round. Rescore with
// the BIT-EXACT np chain (ascending single-acc fmaf), emit top-32 by
// (exact score desc, row asc).
// All candidate keys carry bit31 (positive scores), so P starts at 1<<31.
// ---------------------------------------------------------------------------
__global__ __launch_bounds__(256) void k2_merge_rescore(
    const float* __restrict__ q, const float* __restrict__ kmem,
    const unsigned* __restrict__ cand, int* __restrict__ final_idx)
{
    const int w    = threadIdx.x >> 6;
    const int lane = threadIdx.x & 63;
    const int qid  = blockIdx.x * 4 + w;

    __shared__ int   rows_s[4][MERGE];
    __shared__ float scs_s[4][MERGE];

    // load 96 candidates per lane, coalesced uint4
    unsigned v[NV];
    const uint4* cp4 = reinterpret_cast<const uint4*>(cand + (size_t)qid * CPQ);
    #pragma unroll
    for (int j = 0; j < NV / 4; ++j) {
        const uint4 t = cp4[j * 64 + lane];
        v[j * 4 + 0] = t.x; v[j * 4 + 1] = t.y;
        v[j * 4 + 2] = t.z; v[j * 4 + 3] = t.w;
    }
    // P = 128th largest u32; per-lane count + 6-step shfl reduce per round
    unsigned P = 1u << 31;
    for (int b = 30; b >= 0; --b) {
        const unsigned trial = P | (1u << b);
        int cnt = 0;
        #pragma unroll
        for (int j = 0; j < NV; ++j) cnt += (v[j] >= trial);
        #pragma unroll
        for (int m = 1; m < 64; m <<= 1) cnt += __shfl_xor(cnt, m);
        if (cnt >= MERGE) P = trial;
    }
    int gt = 0, eq = 0;
    #pragma unroll
    for (int j = 0; j < NV; ++j) { gt += (v[j] > P); eq += (v[j] == P); }
    int pgt = gt, peq = eq;
    #pragma unroll
    for (int m = 1; m < 64; m <<= 1) {
        const int ag = __shfl_up(pgt, m);
        const int ae = __shfl_up(peq, m);
        if (lane >= m) { pgt += ag; peq += ae; }
    }
    const int totGT = __shfl(pgt, 63);
    pgt -= gt; peq -= eq;
    const int quotaEq = MERGE - totGT;
    {
        int sgt = pgt, seq = peq;
        #pragma unroll
        for (int j = 0; j < NV; ++j) {
            const int off   = (j & ~3) * 64 + lane * 4 + (j & 3); // u32 offset in query's cand block
            const int strip = off / TOPS;                          // const div -> magic mul
            const int row   = strip * STRIP + (STRIP - 1) - (int)(v[j] & 127u);
            if (v[j] > P) {
                rows_s[w][sgt++] = row;
            } else if (v[j] == P) {
                if (seq < quotaEq) rows_s[w][totGT + seq] = row;
                seq++;
            }
        }
    }
    __syncthreads();

    // bit-exact rescore: 2 interleaved ascending fmaf chains per lane
    {
#pragma clang fp contract(off)
        const float4* qr = reinterpret_cast<const float4*>(q + (size_t)qid * DIM);
        const int ra = rows_s[w][lane];
        const int rb = rows_s[w][lane + 64];
        const float4* ka = reinterpret_cast<const float4*>(kmem + (size_t)ra * DIM);
        const float4* kb = reinterpret_cast<const float4*>(kmem + (size_t)rb * DIM);
        float sa = 0.f, sb = 0.f;
        for (int d4 = 0; d4 < DIM / 4; ++d4) {
            const float4 qv = qr[d4];
            const float4 av = ka[d4];
            const float4 bv = kb[d4];
            sa = __builtin_fmaf(qv.x, av.x, sa); sb = __builtin_fmaf(qv.x, bv.x, sb);
            sa = __builtin_fmaf(qv.y, av.y, sa); sb = __builtin_fmaf(qv.y, bv.y, sb);
            sa = __builtin_fmaf(qv.z, av.z, sa); sb = __builtin_fmaf(qv.z, bv.z, sb);
            sa = __builtin_fmaf(qv.w, av.w, sa); sb = __builtin_fmaf(qv.w, bv.w, sb);
        }
        scs_s[w][lane]      = sa;
        scs_s[w][lane + 64] = sb;
    }
    __syncthreads();

    // exact top-32 of 128 by (score desc, row asc)
    float m0 = scs_s[w][lane],      m1 = scs_s[w][lane + 64];
    const int rr0 = rows_s[w][lane], rr1 = rows_s[w][lane + 64];
    for (int sel = 0; sel < TOPK; ++sel) {
        float bs; int bi;
        if (m0 > m1 || (m0 == m1 && rr0 < rr1)) { bs = m0; bi = rr0; }
        else                                    { bs = m1; bi = rr1; }
        #pragma unroll
        for (int m = 1; m < 64; m <<= 1) {
            const float os = __shfl_xor(bs, m);
            const int   oi = __shfl_xor(bi, m);
            if (os > bs || (os == bs && oi < bi)) { bs = os; bi = oi; }
        }
        if (lane == 0) final_idx[qid * TOPK + sel] = bi;
        if (rr0 == bi) m0 = -FLT_MAX;   // rows unique -> removes exactly winner
        if (rr1 == bi) m1 = -FLT_MAX;
    }
}

// ---------------------------------------------------------------------------
// K3: gather K and V rows into the output (k block then v block, flat f32)
// ---------------------------------------------------------------------------
__global__ __launch_bounds__(128) void k3_gather(
    const float* __restrict__ kmem, const float* __restrict__ vmem,
    const int* __restrict__ final_idx, float* __restrict__ out)
{
    const int b = blockIdx.x;
    const int t = threadIdx.x;
    const int idx = final_idx[b];
    const float4* kr = reinterpret_cast<const float4*>(kmem + (size_t)idx * DIM);
    const float4* vr = reinterpret_cast<const float4*>(vmem + (size_t)idx * DIM);
    float4* ok = reinterpret_cast<float4*>(out + (size_t)b * DIM);
    float4* ov = reinterpret_cast<float4*>(out + (size_t)NQ * TOPK * DIM + (size_t)b * DIM);
    ok[t] = kr[t];
    ov[t] = vr[t];
}

extern "C" void kernel_launch(void* const* d_in, const int* in_sizes, int n_in,
                              void* d_out, int out_size, void* d_ws, size_t ws_size,
                              hipStream_t stream)
{
    const float* q    = (const float*)d_in[0];
    const float* kmem = (const float*)d_in[1];
    const float* vmem = (const float*)d_in[2];
    float* out = (float*)d_out;

    // d_out scratch layout (consumed before K3 overwrites everything):
    // [0, 134217728)            bf16 K
    // [134217728, 136314880)    bf16 q
    // [136314880, 186646528)    packed candidates (u32, 2048 x 6144)
    unsigned char* base = (unsigned char*)d_out;
    unsigned short* kbf = (unsigned short*)base;
    unsigned short* qbf = (unsigned short*)(base + (size_t)MSZ * DIM * 2);
    unsigned* cand = (unsigned*)(base + (size_t)MSZ * DIM * 2 + (size_t)NQ * DIM * 2);
    int* final_idx = (int*)d_ws;   // 256 KB, survives the gather

    k0_convert<<<4096, 256, 0, stream>>>(kmem, kbf, MSZ * DIM / 4);
    k0_convert<<<256, 256, 0, stream>>>(q, qbf, NQ * DIM / 4);
    k1_score_select<<<(NQ / QT) * NSTRIP, 256, 0, stream>>>(qbf, kbf, cand);  // 16384 blocks
    k2_merge_rescore<<<NQ / 4, 256, 0, stream>>>(q, kmem, cand, final_idx);
    k3_gather<<<NQ * TOPK, 128, 0, stream>>>(kmem, vmem, final_idx, out);
}